// Round 3
// baseline (217.395 us; speedup 1.0000x reference)
//
#include <hip/hip_runtime.h>
#include <math.h>

#define D 256
#define H 512
#define TT 10
#define THRESH 0.4f
#define KS 8          // K steps of 32 (D = 256)
#define NT 32         // H / 16 n-tiles

typedef __attribute__((ext_vector_type(8))) short bf16x8;
typedef __attribute__((ext_vector_type(4))) float f32x4;

__device__ inline short f2bf(float x) {
    unsigned u = __builtin_bit_cast(unsigned, x);
    u += 0x7FFFu + ((u >> 16) & 1u);
    return (short)(u >> 16);
}
__device__ inline float bf2f(short h) {
    unsigned u = ((unsigned)(unsigned short)h) << 16;
    return __builtin_bit_cast(float, u);
}

// ---------------------------------------------------------------------------
// K0: swizzle W1 [D][H] f32 -> hi/lo bf16 MFMA B-fragments in ws.
// layout (bf16x8 units): idx = ((n*2 + hl)*8 + k)*64 + lane
//   element i of that bf16x8 = W1[k*32 + (lane>>4)*8 + i][n*16 + (lane&15)]
// ---------------------------------------------------------------------------
__global__ __launch_bounds__(256) void w1_prep(const float* __restrict__ W1,
                                               short* __restrict__ W1s)
{
    const int tid = blockIdx.x * 256 + threadIdx.x;   // 16384 threads
    const int lane = tid & 63;
    const int cell = tid >> 6;                        // 0..255 = (n,k)
    const int k = cell & 7;
    const int n = cell >> 3;
    const int row0 = k * 32 + (lane >> 4) * 8;
    const int col = n * 16 + (lane & 15);
    short hi8[8], lo8[8];
    #pragma unroll
    for (int i = 0; i < 8; ++i) {
        float x = W1[(size_t)(row0 + i) * H + col];
        short h = f2bf(x);
        hi8[i] = h;
        lo8[i] = f2bf(x - bf2f(h));
    }
    size_t bh = ((((size_t)n * 2 + 0) * 8 + k) * 64 + lane) * 8;
    size_t bl = ((((size_t)n * 2 + 1) * 8 + k) * 64 + lane) * 8;
    *reinterpret_cast<bf16x8*>(W1s + bh) = *reinterpret_cast<bf16x8*>(hi8);
    *reinterpret_cast<bf16x8*>(W1s + bl) = *reinterpret_cast<bf16x8*>(lo8);
}

// ---------------------------------------------------------------------------
// K1: gate MLP via split-bf16 MFMA. 1 wave per block, 32 rows per wave.
// B-fragments streamed directly from L1/L2 (W1s is 512 KB, cache-resident).
// No LDS, no barriers, no staging registers.
// ---------------------------------------------------------------------------
__global__ __launch_bounds__(64) void gate_mfma(
    const float* __restrict__ h_sub,
    const short* __restrict__ W1s,
    const float* __restrict__ b1,
    const float* __restrict__ W2,
    const float* __restrict__ b2,
    float* __restrict__ submask)
{
    const int lane = threadIdx.x;        // 0..63
    const int base = blockIdx.x * 32;
    const float bb = b2[0];

    // this wave's 32 rows of h_sub as hi/lo bf16 A-fragments (128 VGPR)
    bf16x8 ahi[2][KS], alo[2][KS];
    #pragma unroll
    for (int s = 0; s < 2; ++s) {
        const int row = base + s * 16 + (lane & 15);
        const float* rp = h_sub + (size_t)row * D + (lane >> 4) * 8;
        #pragma unroll
        for (int k = 0; k < KS; ++k) {
            float x[8];
            *reinterpret_cast<float4*>(&x[0]) =
                *reinterpret_cast<const float4*>(rp + k * 32);
            *reinterpret_cast<float4*>(&x[4]) =
                *reinterpret_cast<const float4*>(rp + k * 32 + 4);
            short hi8[8], lo8[8];
            #pragma unroll
            for (int i = 0; i < 8; ++i) {
                short h = f2bf(x[i]);
                hi8[i] = h;
                lo8[i] = f2bf(x[i] - bf2f(h));
            }
            ahi[s][k] = *reinterpret_cast<bf16x8*>(hi8);
            alo[s][k] = *reinterpret_cast<bf16x8*>(lo8);
        }
    }

    const bf16x8* __restrict__ Wf = reinterpret_cast<const bf16x8*>(W1s);
    float lp[2][4] = {{0.f,0.f,0.f,0.f},{0.f,0.f,0.f,0.f}};

    for (int n = 0; n < NT; ++n) {
        f32x4 a0[2], a1[2], a2[2];
        #pragma unroll
        for (int s = 0; s < 2; ++s) {
            a0[s] = (f32x4){0.f,0.f,0.f,0.f};
            a1[s] = (f32x4){0.f,0.f,0.f,0.f};
            a2[s] = (f32x4){0.f,0.f,0.f,0.f};
        }
        #pragma unroll
        for (int k = 0; k < KS; ++k) {
            bf16x8 bh = Wf[(((size_t)n * 2 + 0) * KS + k) * 64 + lane];
            bf16x8 bl = Wf[(((size_t)n * 2 + 1) * KS + k) * 64 + lane];
            #pragma unroll
            for (int s = 0; s < 2; ++s) {
                a0[s] = __builtin_amdgcn_mfma_f32_16x16x32_bf16(ahi[s][k], bh, a0[s], 0, 0, 0);
                a1[s] = __builtin_amdgcn_mfma_f32_16x16x32_bf16(ahi[s][k], bl, a1[s], 0, 0, 0);
                a2[s] = __builtin_amdgcn_mfma_f32_16x16x32_bf16(alo[s][k], bh, a2[s], 0, 0, 0);
            }
        }
        // epilogue for these 16 hidden cols: +b1, relu, dot W2
        const int h = n * 16 + (lane & 15);
        const float b1h = b1[h], w2h = W2[h];
        #pragma unroll
        for (int s = 0; s < 2; ++s)
            #pragma unroll
            for (int j = 0; j < 4; ++j) {
                float v = a0[s][j] + a1[s][j] + a2[s][j] + b1h;
                v = v > 0.f ? v : 0.f;
                lp[s][j] = fmaf(v, w2h, lp[s][j]);
            }
    }

    // reduce partial logits over the 16 cols (lanes within each 16-lane group)
    #pragma unroll
    for (int m = 1; m < 16; m <<= 1)
        #pragma unroll
        for (int s = 0; s < 2; ++s)
            #pragma unroll
            for (int j = 0; j < 4; ++j)
                lp[s][j] += __shfl_xor(lp[s][j], m);

    if ((lane & 15) == 0) {
        const int g = lane >> 4;
        #pragma unroll
        for (int s = 0; s < 2; ++s)
            #pragma unroll
            for (int j = 0; j < 4; ++j) {
                float logit = lp[s][j] + bb;
                submask[base + s * 16 + g * 4 + j] = 1.f / (1.f + expf(-logit));
            }
    }
}

// ---------------------------------------------------------------------------
// K2: per-graph masked segment mean + cosine + classifier logits
// ---------------------------------------------------------------------------
__global__ __launch_bounds__(256) void seg_kernel(
    const float* __restrict__ h_graph,  // [B][D]
    const float* __restrict__ h_sub,    // [S][D]
    const int*   __restrict__ mask,     // [B][S]
    const float* __restrict__ submask,  // [S]
    const float* __restrict__ Wc,       // [2D][TT]
    const float* __restrict__ bc,       // [TT]
    float* __restrict__ logits,         // [B][TT]
    float* __restrict__ cos_ws,         // [B]
    int S)
{
    const int i = blockIdx.x;
    const int tid = threadIdx.x;
    const int lane = tid & 63;
    const int w = tid >> 6;
    const int* mrow = mask + (size_t)i * S;

    float4 acc = make_float4(0.f, 0.f, 0.f, 0.f);
    int cnt = 0;

    const int per = S >> 2;
    for (int base = w * per; base < (w + 1) * per; base += 256) {
        const int j0 = base + (lane << 2);
        int4 m4 = *reinterpret_cast<const int4*>(mrow + j0);
        unsigned long long bal[4];
        bal[0] = __ballot((m4.x != 0) & (submask[j0 + 0] > THRESH));
        bal[1] = __ballot((m4.y != 0) & (submask[j0 + 1] > THRESH));
        bal[2] = __ballot((m4.z != 0) & (submask[j0 + 2] > THRESH));
        bal[3] = __ballot((m4.w != 0) & (submask[j0 + 3] > THRESH));
        #pragma unroll
        for (int s = 0; s < 4; ++s) {
            unsigned long long b = bal[s];
            while (b) {
                int t = __builtin_ctzll(b);
                b &= b - 1;
                int jj = base + (t << 2) + s;
                float4 hv = *reinterpret_cast<const float4*>(
                    h_sub + (size_t)jj * D + (lane << 2));
                acc.x += hv.x; acc.y += hv.y; acc.z += hv.z; acc.w += hv.w;
                cnt++;
            }
        }
    }

    __shared__ float ssum[4][D];
    __shared__ int   scnt[4];
    *reinterpret_cast<float4*>(&ssum[w][lane << 2]) = acc;
    if (lane == 0) scnt[w] = cnt;
    __syncthreads();

    float a = ssum[0][tid] + ssum[1][tid] + ssum[2][tid] + ssum[3][tid];
    const int c = scnt[0] + scnt[1] + scnt[2] + scnt[3];
    a = (c > 0) ? (a / (float)c) : 0.f;
    const float g = h_graph[(size_t)i * D + tid];

    float r0 = a * a, r1 = g * g, r2 = a * g;
    #pragma unroll
    for (int m = 1; m < 64; m <<= 1) {
        r0 += __shfl_xor(r0, m);
        r1 += __shfl_xor(r1, m);
        r2 += __shfl_xor(r2, m);
    }
    __shared__ float red[4][3];
    if (lane == 0) { red[w][0] = r0; red[w][1] = r1; red[w][2] = r2; }
    __syncthreads();
    if (tid == 0) {
        float a2 = red[0][0] + red[1][0] + red[2][0] + red[3][0];
        float g2 = red[0][1] + red[1][1] + red[2][1] + red[3][1];
        float ag = red[0][2] + red[1][2] + red[2][2] + red[3][2];
        float an = sqrtf(a2), gn = sqrtf(g2);
        float cs = (c > 0) ? (ag / (fmaxf(an, 1e-12f) * fmaxf(gn, 1e-12f))) : 0.f;
        cos_ws[i] = cs;
    }

    float lg[TT];
    #pragma unroll
    for (int t = 0; t < TT; ++t)
        lg[t] = g * Wc[(size_t)tid * TT + t] + a * Wc[(size_t)(D + tid) * TT + t];
    #pragma unroll
    for (int m = 1; m < 64; m <<= 1)
        #pragma unroll
        for (int t = 0; t < TT; ++t) lg[t] += __shfl_xor(lg[t], m);
    __shared__ float lpart[4][TT];
    if (lane == 0)
        #pragma unroll
        for (int t = 0; t < TT; ++t) lpart[w][t] = lg[t];
    __syncthreads();
    if (tid < TT)
        logits[(size_t)i * TT + tid] =
            lpart[0][tid] + lpart[1][tid] + lpart[2][tid] + lpart[3][tid] + bc[tid];
}

// ---------------------------------------------------------------------------
__global__ void loss_kernel(const float* __restrict__ cos_ws,
                            float* __restrict__ out, int B)
{
    const int lane = threadIdx.x;
    float s = 0.f;
    for (int i = lane; i < B; i += 64) s += cos_ws[i];
    #pragma unroll
    for (int m = 1; m < 64; m <<= 1) s += __shfl_xor(s, m);
    if (lane == 0) out[0] = 1.0f - s / (float)B;
}

// ---------------------------------------------------------------------------
extern "C" void kernel_launch(void* const* d_in, const int* in_sizes, int n_in,
                              void* d_out, int out_size, void* d_ws, size_t ws_size,
                              hipStream_t stream)
{
    const float* h_graph = (const float*)d_in[0];
    const float* h_sub   = (const float*)d_in[1];
    const float* W1      = (const float*)d_in[2];
    const float* b1      = (const float*)d_in[3];
    const float* W2      = (const float*)d_in[4];
    const float* b2      = (const float*)d_in[5];
    const float* Wc      = (const float*)d_in[6];
    const float* bc      = (const float*)d_in[7];
    const int*   mask    = (const int*)d_in[8];

    const int B = in_sizes[0] / D;
    const int S = in_sizes[1] / D;

    float* out     = (float*)d_out;
    float* logits  = out;                       // [B*TT]
    float* loss    = out + (size_t)B * TT;      // [1]
    float* submask = loss + 1;                  // [S]

    short* W1s    = (short*)d_ws;                            // 512 KB fragments
    float* cos_ws = (float*)((char*)d_ws + 600 * 1024);      // [B] scratch

    w1_prep<<<64, 256, 0, stream>>>(W1, W1s);
    gate_mfma<<<S / 32, 64, 0, stream>>>(h_sub, W1s, b1, W2, b2, submask);
    seg_kernel<<<B, 256, 0, stream>>>(
        h_graph, h_sub, mask, submask, Wc, bc, logits, cos_ws, S);
    loss_kernel<<<1, 64, 0, stream>>>(cos_ws, loss, B);
}

// Round 4
// 118.298 us; speedup vs baseline: 1.8377x; 1.8377x over previous
//
#include <hip/hip_runtime.h>
#include <math.h>

#define D 256
#define H 512
#define TT 10
#define THRESH 0.4f
#define KS 8          // K steps of 32 (D = 256)
#define NT 32         // H / 16 n-tiles
#define NCHUNK 16     // chunks of 2 n-tiles

typedef __attribute__((ext_vector_type(8))) short bf16x8;
typedef __attribute__((ext_vector_type(4))) float f32x4;

__device__ inline short f2bf(float x) {
    unsigned u = __builtin_bit_cast(unsigned, x);
    u += 0x7FFFu + ((u >> 16) & 1u);
    return (short)(u >> 16);
}
__device__ inline float bf2f(short h) {
    unsigned u = ((unsigned)(unsigned short)h) << 16;
    return __builtin_bit_cast(float, u);
}

// ---------------------------------------------------------------------------
// K0: swizzle W1 [D][H] f32 -> hi/lo bf16 MFMA B-fragments in ws.
// layout (bf16x8 = 16B units): idx = ((n*2 + hl)*8 + k)*64 + lane
//   element i = W1[k*32 + (lane>>4)*8 + i][n*16 + (lane&15)]
// ---------------------------------------------------------------------------
__global__ __launch_bounds__(256) void w1_prep(const float* __restrict__ W1,
                                               short* __restrict__ W1s)
{
    const int tid = blockIdx.x * 256 + threadIdx.x;   // 16384 threads
    const int lane = tid & 63;
    const int cell = tid >> 6;                        // 0..255 = (n,k)
    const int k = cell & 7;
    const int n = cell >> 3;
    const int row0 = k * 32 + (lane >> 4) * 8;
    const int col = n * 16 + (lane & 15);
    short hi8[8], lo8[8];
    #pragma unroll
    for (int i = 0; i < 8; ++i) {
        float x = W1[(size_t)(row0 + i) * H + col];
        short h = f2bf(x);
        hi8[i] = h;
        lo8[i] = f2bf(x - bf2f(h));
    }
    size_t bh = ((((size_t)n * 2 + 0) * 8 + k) * 64 + lane) * 8;
    size_t bl = ((((size_t)n * 2 + 1) * 8 + k) * 64 + lane) * 8;
    *reinterpret_cast<bf16x8*>(W1s + bh) = *reinterpret_cast<bf16x8*>(hi8);
    *reinterpret_cast<bf16x8*>(W1s + bl) = *reinterpret_cast<bf16x8*>(lo8);
}

// ---------------------------------------------------------------------------
// K1: gate MLP via split-bf16 MFMA. 4 waves/block, 128 rows/block.
// W1 frags double-buffered in LDS via global_load_lds(16B), counted vmcnt,
// raw s_barrier (prefetch stays in flight across barriers).
// ---------------------------------------------------------------------------
__global__ __launch_bounds__(256, 2) void gate_mfma(
    const float* __restrict__ h_sub,
    const short* __restrict__ W1s,
    const float* __restrict__ b1,
    const float* __restrict__ W2,
    const float* __restrict__ b2,
    float* __restrict__ submask)
{
    __shared__ __align__(16) short sW[2][16384];   // 2 x 32 KB chunk buffers
    __shared__ float sb1[H], sw2[H];
    const int tid = threadIdx.x;
    const int lane = tid & 63;
    const int w = tid >> 6;
    const int base = blockIdx.x * 128;
    const float bb = b2[0];

    // stage b1 / W2 into LDS (so no stray VMEM during the counted loop)
    {
        int i = tid * 2;
        *reinterpret_cast<float2*>(&sb1[i]) = *reinterpret_cast<const float2*>(&b1[i]);
        *reinterpret_cast<float2*>(&sw2[i]) = *reinterpret_cast<const float2*>(&W2[i]);
    }

    // this wave's 32 rows of h_sub as hi/lo bf16 A-fragments (128 VGPR)
    bf16x8 ahi[2][KS], alo[2][KS];
    #pragma unroll
    for (int s = 0; s < 2; ++s) {
        const int row = base + w * 32 + s * 16 + (lane & 15);
        const float* rp = h_sub + (size_t)row * D + (lane >> 4) * 8;
        #pragma unroll
        for (int k = 0; k < KS; ++k) {
            float x[8];
            *reinterpret_cast<float4*>(&x[0]) =
                *reinterpret_cast<const float4*>(rp + k * 32);
            *reinterpret_cast<float4*>(&x[4]) =
                *reinterpret_cast<const float4*>(rp + k * 32 + 4);
            short hi8[8], lo8[8];
            #pragma unroll
            for (int i = 0; i < 8; ++i) {
                short h = f2bf(x[i]);
                hi8[i] = h;
                lo8[i] = f2bf(x[i] - bf2f(h));
            }
            ahi[s][k] = *reinterpret_cast<bf16x8*>(hi8);
            alo[s][k] = *reinterpret_cast<bf16x8*>(lo8);
        }
    }

    __syncthreads();   // sb1/sw2 visible; drains all prior vmem (clean vmcnt)

    // async stage of one 32 KB chunk (2 n-tiles): 8 global_load_lds per wave
    char* lds0 = (char*)&sW[0][0];
    auto stage = [&](int c, int b) {
        const char* gp = (const char*)W1s + ((size_t)c << 15) + (size_t)tid * 16;
        char* lp0 = lds0 + b * 32768 + w * 1024;
        #pragma unroll
        for (int i = 0; i < 8; ++i) {
            __builtin_amdgcn_global_load_lds(
                (const __attribute__((address_space(1))) void*)(gp + i * 4096),
                (__attribute__((address_space(3))) void*)(lp0 + i * 4096),
                16, 0, 0);
        }
    };

    stage(0, 0);
    stage(1, 1);

    float lp[2][4] = {{0.f,0.f,0.f,0.f},{0.f,0.f,0.f,0.f}};

    for (int c = 0; c < NCHUNK; ++c) {
        // chunk c landed; keep chunk c+1's 8 loads in flight
        if (c < NCHUNK - 1) asm volatile("s_waitcnt vmcnt(8)" ::: "memory");
        else                asm volatile("s_waitcnt vmcnt(0)" ::: "memory");
        __builtin_amdgcn_s_barrier();
        __builtin_amdgcn_sched_barrier(0);

        const short* buf = &sW[c & 1][0];
        #pragma unroll
        for (int t = 0; t < 2; ++t) {
            const int n = c * 2 + t;
            f32x4 a0[2], a1[2], a2[2];
            #pragma unroll
            for (int s = 0; s < 2; ++s) {
                a0[s] = (f32x4){0.f,0.f,0.f,0.f};
                a1[s] = (f32x4){0.f,0.f,0.f,0.f};
                a2[s] = (f32x4){0.f,0.f,0.f,0.f};
            }
            #pragma unroll
            for (int k = 0; k < KS; ++k) {
                const short* fb = buf + ((t * 2 + 0) * 8 + k) * 512 + lane * 8;
                bf16x8 bh = *reinterpret_cast<const bf16x8*>(fb);
                bf16x8 bl = *reinterpret_cast<const bf16x8*>(fb + 8 * 512);
                #pragma unroll
                for (int s = 0; s < 2; ++s) {
                    a0[s] = __builtin_amdgcn_mfma_f32_16x16x32_bf16(ahi[s][k], bh, a0[s], 0, 0, 0);
                    a1[s] = __builtin_amdgcn_mfma_f32_16x16x32_bf16(ahi[s][k], bl, a1[s], 0, 0, 0);
                    a2[s] = __builtin_amdgcn_mfma_f32_16x16x32_bf16(alo[s][k], bh, a2[s], 0, 0, 0);
                }
            }
            const int h = n * 16 + (lane & 15);
            const float b1h = sb1[h], w2h = sw2[h];
            #pragma unroll
            for (int s = 0; s < 2; ++s)
                #pragma unroll
                for (int j = 0; j < 4; ++j) {
                    float v = a0[s][j] + a1[s][j] + a2[s][j] + b1h;
                    v = v > 0.f ? v : 0.f;
                    lp[s][j] = fmaf(v, w2h, lp[s][j]);
                }
        }

        __builtin_amdgcn_sched_barrier(0);
        __builtin_amdgcn_s_barrier();        // all waves done reading buf[c&1]
        if (c < NCHUNK - 2) stage(c + 2, c & 1);
    }

    // reduce partial logits over 16 h-cols (within 16-lane groups)
    #pragma unroll
    for (int m = 1; m < 16; m <<= 1)
        #pragma unroll
        for (int s = 0; s < 2; ++s)
            #pragma unroll
            for (int j = 0; j < 4; ++j)
                lp[s][j] += __shfl_xor(lp[s][j], m);

    if ((lane & 15) == 0) {
        const int g = lane >> 4;
        #pragma unroll
        for (int s = 0; s < 2; ++s)
            #pragma unroll
            for (int j = 0; j < 4; ++j) {
                float logit = lp[s][j] + bb;
                submask[base + w * 32 + s * 16 + g * 4 + j] =
                    1.f / (1.f + expf(-logit));
            }
    }
}

// ---------------------------------------------------------------------------
// K2: per-graph masked segment mean + cosine + classifier logits
// ---------------------------------------------------------------------------
__global__ __launch_bounds__(256) void seg_kernel(
    const float* __restrict__ h_graph,  // [B][D]
    const float* __restrict__ h_sub,    // [S][D]
    const int*   __restrict__ mask,     // [B][S]
    const float* __restrict__ submask,  // [S]
    const float* __restrict__ Wc,       // [2D][TT]
    const float* __restrict__ bc,       // [TT]
    float* __restrict__ logits,         // [B][TT]
    float* __restrict__ cos_ws,         // [B]
    int S)
{
    const int i = blockIdx.x;
    const int tid = threadIdx.x;
    const int lane = tid & 63;
    const int w = tid >> 6;
    const int* mrow = mask + (size_t)i * S;

    float4 acc = make_float4(0.f, 0.f, 0.f, 0.f);
    int cnt = 0;

    const int per = S >> 2;
    for (int base = w * per; base < (w + 1) * per; base += 256) {
        const int j0 = base + (lane << 2);
        int4 m4 = *reinterpret_cast<const int4*>(mrow + j0);
        unsigned long long bal[4];
        bal[0] = __ballot((m4.x != 0) & (submask[j0 + 0] > THRESH));
        bal[1] = __ballot((m4.y != 0) & (submask[j0 + 1] > THRESH));
        bal[2] = __ballot((m4.z != 0) & (submask[j0 + 2] > THRESH));
        bal[3] = __ballot((m4.w != 0) & (submask[j0 + 3] > THRESH));
        #pragma unroll
        for (int s = 0; s < 4; ++s) {
            unsigned long long b = bal[s];
            while (b) {
                int t = __builtin_ctzll(b);
                b &= b - 1;
                int jj = base + (t << 2) + s;
                float4 hv = *reinterpret_cast<const float4*>(
                    h_sub + (size_t)jj * D + (lane << 2));
                acc.x += hv.x; acc.y += hv.y; acc.z += hv.z; acc.w += hv.w;
                cnt++;
            }
        }
    }

    __shared__ float ssum[4][D];
    __shared__ int   scnt[4];
    *reinterpret_cast<float4*>(&ssum[w][lane << 2]) = acc;
    if (lane == 0) scnt[w] = cnt;
    __syncthreads();

    float a = ssum[0][tid] + ssum[1][tid] + ssum[2][tid] + ssum[3][tid];
    const int c = scnt[0] + scnt[1] + scnt[2] + scnt[3];
    a = (c > 0) ? (a / (float)c) : 0.f;
    const float g = h_graph[(size_t)i * D + tid];

    float r0 = a * a, r1 = g * g, r2 = a * g;
    #pragma unroll
    for (int m = 1; m < 64; m <<= 1) {
        r0 += __shfl_xor(r0, m);
        r1 += __shfl_xor(r1, m);
        r2 += __shfl_xor(r2, m);
    }
    __shared__ float red[4][3];
    if (lane == 0) { red[w][0] = r0; red[w][1] = r1; red[w][2] = r2; }
    __syncthreads();
    if (tid == 0) {
        float a2 = red[0][0] + red[1][0] + red[2][0] + red[3][0];
        float g2 = red[0][1] + red[1][1] + red[2][1] + red[3][1];
        float ag = red[0][2] + red[1][2] + red[2][2] + red[3][2];
        float an = sqrtf(a2), gn = sqrtf(g2);
        float cs = (c > 0) ? (ag / (fmaxf(an, 1e-12f) * fmaxf(gn, 1e-12f))) : 0.f;
        cos_ws[i] = cs;
    }

    float lg[TT];
    #pragma unroll
    for (int t = 0; t < TT; ++t)
        lg[t] = g * Wc[(size_t)tid * TT + t] + a * Wc[(size_t)(D + tid) * TT + t];
    #pragma unroll
    for (int m = 1; m < 64; m <<= 1)
        #pragma unroll
        for (int t = 0; t < TT; ++t) lg[t] += __shfl_xor(lg[t], m);
    __shared__ float lpart[4][TT];
    if (lane == 0)
        #pragma unroll
        for (int t = 0; t < TT; ++t) lpart[w][t] = lg[t];
    __syncthreads();
    if (tid < TT)
        logits[(size_t)i * TT + tid] =
            lpart[0][tid] + lpart[1][tid] + lpart[2][tid] + lpart[3][tid] + bc[tid];
}

// ---------------------------------------------------------------------------
__global__ void loss_kernel(const float* __restrict__ cos_ws,
                            float* __restrict__ out, int B)
{
    const int lane = threadIdx.x;
    float s = 0.f;
    for (int i = lane; i < B; i += 64) s += cos_ws[i];
    #pragma unroll
    for (int m = 1; m < 64; m <<= 1) s += __shfl_xor(s, m);
    if (lane == 0) out[0] = 1.0f - s / (float)B;
}

// ---------------------------------------------------------------------------
extern "C" void kernel_launch(void* const* d_in, const int* in_sizes, int n_in,
                              void* d_out, int out_size, void* d_ws, size_t ws_size,
                              hipStream_t stream)
{
    const float* h_graph = (const float*)d_in[0];
    const float* h_sub   = (const float*)d_in[1];
    const float* W1      = (const float*)d_in[2];
    const float* b1      = (const float*)d_in[3];
    const float* W2      = (const float*)d_in[4];
    const float* b2      = (const float*)d_in[5];
    const float* Wc      = (const float*)d_in[6];
    const float* bc      = (const float*)d_in[7];
    const int*   mask    = (const int*)d_in[8];

    const int B = in_sizes[0] / D;
    const int S = in_sizes[1] / D;

    float* out     = (float*)d_out;
    float* logits  = out;                       // [B*TT]
    float* loss    = out + (size_t)B * TT;      // [1]
    float* submask = loss + 1;                  // [S]

    short* W1s    = (short*)d_ws;                            // 512 KB fragments
    float* cos_ws = (float*)((char*)d_ws + 600 * 1024);      // [B] scratch

    w1_prep<<<64, 256, 0, stream>>>(W1, W1s);
    gate_mfma<<<S / 128, 256, 0, stream>>>(h_sub, W1s, b1, W2, b2, submask);
    seg_kernel<<<B, 256, 0, stream>>>(
        h_graph, h_sub, mask, submask, Wc, bc, logits, cos_ws, S);
    loss_kernel<<<1, 64, 0, stream>>>(cos_ws, loss, B);
}

// Round 5
// 101.006 us; speedup vs baseline: 2.1523x; 1.1712x over previous
//
#include <hip/hip_runtime.h>
#include <math.h>

#define D 256
#define H 512
#define TT 10
#define THRESH 0.4f
#define KS 8          // K steps of 32 (D = 256)
#define NT 32         // H / 16 n-tiles
#define NCHUNK 16     // chunks of 2 n-tiles
#define NSPLIT 4      // scan blocks per graph

typedef __attribute__((ext_vector_type(8))) short bf16x8;
typedef __attribute__((ext_vector_type(4))) float f32x4;

__device__ inline short f2bf(float x) {
    unsigned u = __builtin_bit_cast(unsigned, x);
    u += 0x7FFFu + ((u >> 16) & 1u);
    return (short)(u >> 16);
}
__device__ inline float bf2f(short h) {
    unsigned u = ((unsigned)(unsigned short)h) << 16;
    return __builtin_bit_cast(float, u);
}

// ---------------------------------------------------------------------------
// K0: swizzle W1 [D][H] f32 -> hi/lo bf16 MFMA B-fragments in ws.
// ---------------------------------------------------------------------------
__global__ __launch_bounds__(256) void w1_prep(const float* __restrict__ W1,
                                               short* __restrict__ W1s)
{
    const int tid = blockIdx.x * 256 + threadIdx.x;   // 16384 threads
    const int lane = tid & 63;
    const int cell = tid >> 6;                        // 0..255 = (n,k)
    const int k = cell & 7;
    const int n = cell >> 3;
    const int row0 = k * 32 + (lane >> 4) * 8;
    const int col = n * 16 + (lane & 15);
    short hi8[8], lo8[8];
    #pragma unroll
    for (int i = 0; i < 8; ++i) {
        float x = W1[(size_t)(row0 + i) * H + col];
        short h = f2bf(x);
        hi8[i] = h;
        lo8[i] = f2bf(x - bf2f(h));
    }
    size_t bh = ((((size_t)n * 2 + 0) * 8 + k) * 64 + lane) * 8;
    size_t bl = ((((size_t)n * 2 + 1) * 8 + k) * 64 + lane) * 8;
    *reinterpret_cast<bf16x8*>(W1s + bh) = *reinterpret_cast<bf16x8*>(hi8);
    *reinterpret_cast<bf16x8*>(W1s + bl) = *reinterpret_cast<bf16x8*>(lo8);
}

// ---------------------------------------------------------------------------
// K1: gate MLP via split-bf16 MFMA + gate bit-array emission.
// ---------------------------------------------------------------------------
__global__ __launch_bounds__(256, 2) void gate_mfma(
    const float* __restrict__ h_sub,
    const short* __restrict__ W1s,
    const float* __restrict__ b1,
    const float* __restrict__ W2,
    const float* __restrict__ b2,
    float* __restrict__ submask,
    unsigned* __restrict__ gbits)      // [S/32]
{
    __shared__ __align__(16) short sW[2][16384];   // 2 x 32 KB chunk buffers
    __shared__ float sb1[H], sw2[H];
    const int tid = threadIdx.x;
    const int lane = tid & 63;
    const int w = tid >> 6;
    const int base = blockIdx.x * 128;
    const float bb = b2[0];

    {
        int i = tid * 2;
        *reinterpret_cast<float2*>(&sb1[i]) = *reinterpret_cast<const float2*>(&b1[i]);
        *reinterpret_cast<float2*>(&sw2[i]) = *reinterpret_cast<const float2*>(&W2[i]);
    }

    // this wave's 32 rows of h_sub as hi/lo bf16 A-fragments (128 VGPR)
    bf16x8 ahi[2][KS], alo[2][KS];
    #pragma unroll
    for (int s = 0; s < 2; ++s) {
        const int row = base + w * 32 + s * 16 + (lane & 15);
        const float* rp = h_sub + (size_t)row * D + (lane >> 4) * 8;
        #pragma unroll
        for (int k = 0; k < KS; ++k) {
            float x[8];
            *reinterpret_cast<float4*>(&x[0]) =
                *reinterpret_cast<const float4*>(rp + k * 32);
            *reinterpret_cast<float4*>(&x[4]) =
                *reinterpret_cast<const float4*>(rp + k * 32 + 4);
            short hi8[8], lo8[8];
            #pragma unroll
            for (int i = 0; i < 8; ++i) {
                short h = f2bf(x[i]);
                hi8[i] = h;
                lo8[i] = f2bf(x[i] - bf2f(h));
            }
            ahi[s][k] = *reinterpret_cast<bf16x8*>(hi8);
            alo[s][k] = *reinterpret_cast<bf16x8*>(lo8);
        }
    }

    __syncthreads();   // sb1/sw2 visible; drains all prior vmem (clean vmcnt)

    char* lds0 = (char*)&sW[0][0];
    auto stage = [&](int c, int b) {
        const char* gp = (const char*)W1s + ((size_t)c << 15) + (size_t)tid * 16;
        char* lp0 = lds0 + b * 32768 + w * 1024;
        #pragma unroll
        for (int i = 0; i < 8; ++i) {
            __builtin_amdgcn_global_load_lds(
                (const __attribute__((address_space(1))) void*)(gp + i * 4096),
                (__attribute__((address_space(3))) void*)(lp0 + i * 4096),
                16, 0, 0);
        }
    };

    stage(0, 0);
    stage(1, 1);

    float lp[2][4] = {{0.f,0.f,0.f,0.f},{0.f,0.f,0.f,0.f}};

    for (int c = 0; c < NCHUNK; ++c) {
        if (c < NCHUNK - 1) asm volatile("s_waitcnt vmcnt(8)" ::: "memory");
        else                asm volatile("s_waitcnt vmcnt(0)" ::: "memory");
        __builtin_amdgcn_s_barrier();
        __builtin_amdgcn_sched_barrier(0);

        const short* buf = &sW[c & 1][0];
        #pragma unroll
        for (int t = 0; t < 2; ++t) {
            const int n = c * 2 + t;
            f32x4 a0[2], a1[2], a2[2];
            #pragma unroll
            for (int s = 0; s < 2; ++s) {
                a0[s] = (f32x4){0.f,0.f,0.f,0.f};
                a1[s] = (f32x4){0.f,0.f,0.f,0.f};
                a2[s] = (f32x4){0.f,0.f,0.f,0.f};
            }
            #pragma unroll
            for (int k = 0; k < KS; ++k) {
                const short* fb = buf + ((t * 2 + 0) * 8 + k) * 512 + lane * 8;
                bf16x8 bh = *reinterpret_cast<const bf16x8*>(fb);
                bf16x8 bl = *reinterpret_cast<const bf16x8*>(fb + 8 * 512);
                #pragma unroll
                for (int s = 0; s < 2; ++s) {
                    a0[s] = __builtin_amdgcn_mfma_f32_16x16x32_bf16(ahi[s][k], bh, a0[s], 0, 0, 0);
                    a1[s] = __builtin_amdgcn_mfma_f32_16x16x32_bf16(ahi[s][k], bl, a1[s], 0, 0, 0);
                    a2[s] = __builtin_amdgcn_mfma_f32_16x16x32_bf16(alo[s][k], bh, a2[s], 0, 0, 0);
                }
            }
            const int h = n * 16 + (lane & 15);
            const float b1h = sb1[h], w2h = sw2[h];
            #pragma unroll
            for (int s = 0; s < 2; ++s)
                #pragma unroll
                for (int j = 0; j < 4; ++j) {
                    float v = a0[s][j] + a1[s][j] + a2[s][j] + b1h;
                    v = v > 0.f ? v : 0.f;
                    lp[s][j] = fmaf(v, w2h, lp[s][j]);
                }
        }

        __builtin_amdgcn_sched_barrier(0);
        __builtin_amdgcn_s_barrier();        // all waves done reading buf[c&1]
        if (c < NCHUNK - 2) stage(c + 2, c & 1);
    }

    // butterfly: all 16 lanes of each group end with the full logit sums
    #pragma unroll
    for (int m = 1; m < 16; m <<= 1)
        #pragma unroll
        for (int s = 0; s < 2; ++s)
            #pragma unroll
            for (int j = 0; j < 4; ++j)
                lp[s][j] += __shfl_xor(lp[s][j], m);

    // gate values + bit word for this wave's 32 rows
    const int g = lane >> 4;
    float sig[2][4];
    unsigned bits = 0;
    #pragma unroll
    for (int s = 0; s < 2; ++s)
        #pragma unroll
        for (int j = 0; j < 4; ++j) {
            sig[s][j] = 1.f / (1.f + expf(-(lp[s][j] + bb)));
            if (sig[s][j] > THRESH) bits |= 1u << (s * 16 + g * 4 + j);
        }
    bits |= __shfl_xor(bits, 16);
    bits |= __shfl_xor(bits, 32);
    if (lane == 0) gbits[blockIdx.x * 4 + w] = bits;

    if ((lane & 15) == 0)
        #pragma unroll
        for (int s = 0; s < 2; ++s)
            #pragma unroll
            for (int j = 0; j < 4; ++j)
                submask[base + w * 32 + s * 16 + g * 4 + j] = sig[s][j];
}

// ---------------------------------------------------------------------------
// K2a: mask scan, NSPLIT blocks per graph -> partial sums/counts in ws
// ---------------------------------------------------------------------------
__global__ __launch_bounds__(256) void seg_scan(
    const float* __restrict__ h_sub,    // [S][D]
    const int*   __restrict__ mask,     // [B][S]
    const unsigned* __restrict__ gbits, // [S/32]
    float* __restrict__ psum,           // [B*NSPLIT][D]
    int*   __restrict__ pcnt,           // [B*NSPLIT]
    int S)
{
    const int i = blockIdx.x / NSPLIT;
    const int p = blockIdx.x % NSPLIT;
    const int tid = threadIdx.x;
    const int lane = tid & 63;
    const int w = tid >> 6;
    const int seg = S / NSPLIT;                 // 16384
    const int start = p * seg;
    const int* mrow = mask + (size_t)i * S + start;

    __shared__ unsigned sbits[2048 / NSPLIT];   // 512 words = 2 KB
    {
        const int nw = seg / 32;                // 512
        for (int t = tid; t < nw; t += 256) sbits[t] = gbits[(start >> 5) + t];
    }
    __syncthreads();

    float4 acc = make_float4(0.f, 0.f, 0.f, 0.f);
    int cnt = 0;

    const int per = seg / 4;                    // per wave: 4096
    for (int base = w * per; base < (w + 1) * per; base += 256) {
        const int j0 = base + (lane << 2);
        int4 m4 = *reinterpret_cast<const int4*>(mrow + j0);
        const unsigned bw = sbits[j0 >> 5];
        const int sh = j0 & 31;
        unsigned long long bal[4];
        bal[0] = __ballot((m4.x != 0) & ((bw >> (sh + 0)) & 1u));
        bal[1] = __ballot((m4.y != 0) & ((bw >> (sh + 1)) & 1u));
        bal[2] = __ballot((m4.z != 0) & ((bw >> (sh + 2)) & 1u));
        bal[3] = __ballot((m4.w != 0) & ((bw >> (sh + 3)) & 1u));
        #pragma unroll
        for (int s = 0; s < 4; ++s) {
            unsigned long long b = bal[s];
            while (b) {
                int t = __builtin_ctzll(b);
                b &= b - 1;
                int jj = start + base + (t << 2) + s;
                float4 hv = *reinterpret_cast<const float4*>(
                    h_sub + (size_t)jj * D + (lane << 2));
                acc.x += hv.x; acc.y += hv.y; acc.z += hv.z; acc.w += hv.w;
                cnt++;
            }
        }
    }

    __shared__ float ssum[4][D];
    __shared__ int   scnt[4];
    *reinterpret_cast<float4*>(&ssum[w][lane << 2]) = acc;
    if (lane == 0) scnt[w] = cnt;
    __syncthreads();

    // thread tid owns component d = tid
    float a = ssum[0][tid] + ssum[1][tid] + ssum[2][tid] + ssum[3][tid];
    psum[(size_t)blockIdx.x * D + tid] = a;
    if (tid == 0) pcnt[blockIdx.x] = scnt[0] + scnt[1] + scnt[2] + scnt[3];
}

// ---------------------------------------------------------------------------
// K2b: combine partials -> mean, cosine, classifier logits
// ---------------------------------------------------------------------------
__global__ __launch_bounds__(256) void seg_combine(
    const float* __restrict__ h_graph,  // [B][D]
    const float* __restrict__ psum,     // [B*NSPLIT][D]
    const int*   __restrict__ pcnt,     // [B*NSPLIT]
    const float* __restrict__ Wc,       // [2D][TT]
    const float* __restrict__ bc,       // [TT]
    float* __restrict__ logits,         // [B][TT]
    float* __restrict__ cos_ws)         // [B]
{
    const int i = blockIdx.x;
    const int tid = threadIdx.x;
    const int lane = tid & 63;
    const int w = tid >> 6;

    float a = 0.f;
    int c = 0;
    #pragma unroll
    for (int p = 0; p < NSPLIT; ++p) {
        a += psum[((size_t)i * NSPLIT + p) * D + tid];
        c += pcnt[i * NSPLIT + p];
    }
    a = (c > 0) ? (a / (float)c) : 0.f;
    const float g = h_graph[(size_t)i * D + tid];

    float r0 = a * a, r1 = g * g, r2 = a * g;
    #pragma unroll
    for (int m = 1; m < 64; m <<= 1) {
        r0 += __shfl_xor(r0, m);
        r1 += __shfl_xor(r1, m);
        r2 += __shfl_xor(r2, m);
    }
    __shared__ float red[4][3];
    if (lane == 0) { red[w][0] = r0; red[w][1] = r1; red[w][2] = r2; }
    __syncthreads();
    if (tid == 0) {
        float a2 = red[0][0] + red[1][0] + red[2][0] + red[3][0];
        float g2 = red[0][1] + red[1][1] + red[2][1] + red[3][1];
        float ag = red[0][2] + red[1][2] + red[2][2] + red[3][2];
        float an = sqrtf(a2), gn = sqrtf(g2);
        float cs = (c > 0) ? (ag / (fmaxf(an, 1e-12f) * fmaxf(gn, 1e-12f))) : 0.f;
        cos_ws[i] = cs;
    }

    float lg[TT];
    #pragma unroll
    for (int t = 0; t < TT; ++t)
        lg[t] = g * Wc[(size_t)tid * TT + t] + a * Wc[(size_t)(D + tid) * TT + t];
    #pragma unroll
    for (int m = 1; m < 64; m <<= 1)
        #pragma unroll
        for (int t = 0; t < TT; ++t) lg[t] += __shfl_xor(lg[t], m);
    __shared__ float lpart[4][TT];
    if (lane == 0)
        #pragma unroll
        for (int t = 0; t < TT; ++t) lpart[w][t] = lg[t];
    __syncthreads();
    if (tid < TT)
        logits[(size_t)i * TT + tid] =
            lpart[0][tid] + lpart[1][tid] + lpart[2][tid] + lpart[3][tid] + bc[tid];
}

// ---------------------------------------------------------------------------
__global__ void loss_kernel(const float* __restrict__ cos_ws,
                            float* __restrict__ out, int B)
{
    const int lane = threadIdx.x;
    float s = 0.f;
    for (int i = lane; i < B; i += 64) s += cos_ws[i];
    #pragma unroll
    for (int m = 1; m < 64; m <<= 1) s += __shfl_xor(s, m);
    if (lane == 0) out[0] = 1.0f - s / (float)B;
}

// ---------------------------------------------------------------------------
extern "C" void kernel_launch(void* const* d_in, const int* in_sizes, int n_in,
                              void* d_out, int out_size, void* d_ws, size_t ws_size,
                              hipStream_t stream)
{
    const float* h_graph = (const float*)d_in[0];
    const float* h_sub   = (const float*)d_in[1];
    const float* W1      = (const float*)d_in[2];
    const float* b1      = (const float*)d_in[3];
    const float* W2      = (const float*)d_in[4];
    const float* b2      = (const float*)d_in[5];
    const float* Wc      = (const float*)d_in[6];
    const float* bc      = (const float*)d_in[7];
    const int*   mask    = (const int*)d_in[8];

    const int B = in_sizes[0] / D;
    const int S = in_sizes[1] / D;

    float* out     = (float*)d_out;
    float* logits  = out;                       // [B*TT]
    float* loss    = out + (size_t)B * TT;      // [1]
    float* submask = loss + 1;                  // [S]

    char* ws = (char*)d_ws;
    short*    W1s    = (short*)ws;                       // 512 KB
    unsigned* gbits  = (unsigned*)(ws + 512 * 1024);     // 8 KB
    int*      pcnt   = (int*)(ws + 528 * 1024);          // 8 KB
    float*    cos_ws = (float*)(ws + 544 * 1024);        // 2 KB
    float*    psum   = (float*)(ws + 1024 * 1024);       // 2 MB

    w1_prep<<<64, 256, 0, stream>>>(W1, W1s);
    gate_mfma<<<S / 128, 256, 0, stream>>>(h_sub, W1s, b1, W2, b2, submask, gbits);
    seg_scan<<<B * NSPLIT, 256, 0, stream>>>(h_sub, mask, gbits, psum, pcnt, S);
    seg_combine<<<B, 256, 0, stream>>>(h_graph, psum, pcnt, Wc, bc, logits, cos_ws);
    loss_kernel<<<1, 64, 0, stream>>>(cos_ws, loss, B);
}

// Round 6
// 96.893 us; speedup vs baseline: 2.2437x; 1.0424x over previous
//
#include <hip/hip_runtime.h>
#include <math.h>

#define D 256
#define H 512
#define TT 10
#define THRESH 0.4f
#define KS 8          // K steps of 32 (D = 256)
#define NSPLIT 4      // scan blocks per graph

typedef __attribute__((ext_vector_type(8))) short bf16x8;
typedef __attribute__((ext_vector_type(4))) float f32x4;

__device__ inline short f2bf(float x) {
    unsigned u = __builtin_bit_cast(unsigned, x);
    u += 0x7FFFu + ((u >> 16) & 1u);
    return (short)(u >> 16);
}
__device__ inline float bf2f(short h) {
    unsigned u = ((unsigned)(unsigned short)h) << 16;
    return __builtin_bit_cast(float, u);
}

// ---------------------------------------------------------------------------
// K0: swizzle W1 [D][H] f32 -> hi/lo bf16 MFMA B-fragments in ws.
// layout (bf16x8 = 16B units): idx = ((n*2 + hl)*8 + k)*64 + lane
//   element i = W1[k*32 + (lane>>4)*8 + i][n*16 + (lane&15)]
// -> each n-tile is a contiguous 16 KB chunk (hi 8 KB | lo 8 KB);
//    n-tiles 0..15 = first 256 KB (H cols 0..255), 16..31 = second 256 KB.
// ---------------------------------------------------------------------------
__global__ __launch_bounds__(256) void w1_prep(const float* __restrict__ W1,
                                               short* __restrict__ W1s)
{
    const int tid = blockIdx.x * 256 + threadIdx.x;   // 16384 threads
    const int lane = tid & 63;
    const int cell = tid >> 6;                        // 0..255 = (n,k)
    const int k = cell & 7;
    const int n = cell >> 3;
    const int row0 = k * 32 + (lane >> 4) * 8;
    const int col = n * 16 + (lane & 15);
    short hi8[8], lo8[8];
    #pragma unroll
    for (int i = 0; i < 8; ++i) {
        float x = W1[(size_t)(row0 + i) * H + col];
        short h = f2bf(x);
        hi8[i] = h;
        lo8[i] = f2bf(x - bf2f(h));
    }
    size_t bh = ((((size_t)n * 2 + 0) * 8 + k) * 64 + lane) * 8;
    size_t bl = ((((size_t)n * 2 + 1) * 8 + k) * 64 + lane) * 8;
    *reinterpret_cast<bf16x8*>(W1s + bh) = *reinterpret_cast<bf16x8*>(hi8);
    *reinterpret_cast<bf16x8*>(W1s + bl) = *reinterpret_cast<bf16x8*>(lo8);
}

// ---------------------------------------------------------------------------
// K1: gate MLP, 2-term split-bf16 MFMA (A=bf16(x), B=hi+lo exact split).
// 512 threads = 8 waves = 4 row-groups x 2 H-halves; 128 rows/block.
// Each H-half streams its own 256 KB of W1 frags: 16 KB chunks, double-
// buffered global_load_lds(16B), counted vmcnt(4), raw s_barrier.
// 16 waves/CU (4/SIMD) at VGPR<=128, LDS ~70 KB.
// ---------------------------------------------------------------------------
__global__ __launch_bounds__(512, 4) void gate_mfma(
    const float* __restrict__ h_sub,
    const short* __restrict__ W1s,
    const float* __restrict__ b1,
    const float* __restrict__ W2,
    const float* __restrict__ b2,
    float* __restrict__ submask,
    unsigned* __restrict__ gbits)      // [S/32]
{
    __shared__ __align__(16) short sW[4][8192];   // [half*2+buf][16 KB]
    __shared__ float sb1[H], sw2[H];
    __shared__ float red[8][32];
    const int tid = threadIdx.x;       // 0..511
    const int lane = tid & 63;
    const int w = tid >> 6;            // 0..7
    const int half = w >> 2;           // H-half
    const int wr = w & 3;              // row-group
    const int base = blockIdx.x * 128;
    const float bb = b2[0];

    sb1[tid] = b1[tid];
    sw2[tid] = W2[tid];

    // A fragments (hi only): rows base + wr*32 + s*16 + (lane&15)
    bf16x8 ahi[2][KS];
    #pragma unroll
    for (int s = 0; s < 2; ++s) {
        const int row = base + wr * 32 + s * 16 + (lane & 15);
        const float* rp = h_sub + (size_t)row * D + (lane >> 4) * 8;
        #pragma unroll
        for (int k = 0; k < KS; ++k) {
            float x[8];
            *reinterpret_cast<float4*>(&x[0]) =
                *reinterpret_cast<const float4*>(rp + k * 32);
            *reinterpret_cast<float4*>(&x[4]) =
                *reinterpret_cast<const float4*>(rp + k * 32 + 4);
            short hi8[8];
            #pragma unroll
            for (int i = 0; i < 8; ++i) hi8[i] = f2bf(x[i]);
            ahi[s][k] = *reinterpret_cast<bf16x8*>(hi8);
        }
    }

    __syncthreads();   // sb1/sw2 visible; all prologue vmem drained

    // stage one 16 KB chunk (n-tile half*16+c) for this wave's half
    const int g256 = wr * 64 + lane;                  // 0..255 in half-group
    const char* gbase = (const char*)W1s + (size_t)half * 262144;
    char* lbase = (char*)&sW[half * 2][0];
    auto stage = [&](int c, int b) {
        const char* gp = gbase + (size_t)c * 16384 + (size_t)g256 * 16;
        char* lp0 = lbase + b * 16384 + wr * 1024 + lane * 16;
        #pragma unroll
        for (int i = 0; i < 4; ++i) {
            __builtin_amdgcn_global_load_lds(
                (const __attribute__((address_space(1))) void*)(gp + i * 4096),
                (__attribute__((address_space(3))) void*)(lp0 + i * 4096),
                16, 0, 0);
        }
    };

    stage(0, 0);
    stage(1, 1);

    float lp[2][4] = {{0.f,0.f,0.f,0.f},{0.f,0.f,0.f,0.f}};

    for (int c = 0; c < 16; ++c) {
        if (c < 15) asm volatile("s_waitcnt vmcnt(4)" ::: "memory");
        else        asm volatile("s_waitcnt vmcnt(0)" ::: "memory");
        __builtin_amdgcn_s_barrier();
        __builtin_amdgcn_sched_barrier(0);

        const short* buf = &sW[half * 2 + (c & 1)][0];
        f32x4 acc[2];
        acc[0] = (f32x4){0.f,0.f,0.f,0.f};
        acc[1] = (f32x4){0.f,0.f,0.f,0.f};
        #pragma unroll
        for (int k = 0; k < KS; ++k) {
            const short* fb = buf + (k * 64 + lane) * 8;
            bf16x8 bh = *reinterpret_cast<const bf16x8*>(fb);
            bf16x8 bl = *reinterpret_cast<const bf16x8*>(fb + 4096);
            #pragma unroll
            for (int s = 0; s < 2; ++s) {
                acc[s] = __builtin_amdgcn_mfma_f32_16x16x32_bf16(ahi[s][k], bl, acc[s], 0, 0, 0);
                acc[s] = __builtin_amdgcn_mfma_f32_16x16x32_bf16(ahi[s][k], bh, acc[s], 0, 0, 0);
            }
        }
        // epilogue for these 16 hidden cols of this half
        const int h = half * 256 + c * 16 + (lane & 15);
        const float b1h = sb1[h], w2h = sw2[h];
        #pragma unroll
        for (int s = 0; s < 2; ++s)
            #pragma unroll
            for (int j = 0; j < 4; ++j) {
                float v = acc[s][j] + b1h;
                v = v > 0.f ? v : 0.f;
                lp[s][j] = fmaf(v, w2h, lp[s][j]);
            }

        __builtin_amdgcn_sched_barrier(0);
        __builtin_amdgcn_s_barrier();        // all waves done reading buf
        if (c < 14) stage(c + 2, c & 1);
    }

    // butterfly over the 16 h-cols (low 4 lane bits)
    #pragma unroll
    for (int m = 1; m < 16; m <<= 1)
        #pragma unroll
        for (int s = 0; s < 2; ++s)
            #pragma unroll
            for (int j = 0; j < 4; ++j)
                lp[s][j] += __shfl_xor(lp[s][j], m);

    // write this wave's 32-row partials; combine across halves
    if ((lane & 15) == 0) {
        const int g = lane >> 4;
        #pragma unroll
        for (int s = 0; s < 2; ++s)
            #pragma unroll
            for (int j = 0; j < 4; ++j)
                red[w][s * 16 + g * 4 + j] = lp[s][j];
    }
    __syncthreads();

    if (half == 0) {
        const bool act = lane < 32;
        float sig = 0.f;
        if (act) {
            float logit = red[wr][lane] + red[4 + wr][lane] + bb;
            sig = 1.f / (1.f + expf(-logit));
        }
        unsigned long long bal = __ballot(act && (sig > THRESH));
        if (act) submask[base + wr * 32 + lane] = sig;
        if (lane == 0) gbits[blockIdx.x * 4 + wr] = (unsigned)bal;
    }
}

// ---------------------------------------------------------------------------
// K2a: mask scan, NSPLIT blocks per graph -> partial sums/counts in ws
// ---------------------------------------------------------------------------
__global__ __launch_bounds__(256) void seg_scan(
    const float* __restrict__ h_sub,    // [S][D]
    const int*   __restrict__ mask,     // [B][S]
    const unsigned* __restrict__ gbits, // [S/32]
    float* __restrict__ psum,           // [B*NSPLIT][D]
    int*   __restrict__ pcnt,           // [B*NSPLIT]
    int S)
{
    const int i = blockIdx.x / NSPLIT;
    const int p = blockIdx.x % NSPLIT;
    const int tid = threadIdx.x;
    const int lane = tid & 63;
    const int w = tid >> 6;
    const int seg = S / NSPLIT;                 // 16384
    const int start = p * seg;
    const int* mrow = mask + (size_t)i * S + start;

    __shared__ unsigned sbits[2048 / NSPLIT];   // 512 words = 2 KB
    {
        const int nw = seg / 32;                // 512
        for (int t = tid; t < nw; t += 256) sbits[t] = gbits[(start >> 5) + t];
    }
    __syncthreads();

    float4 acc = make_float4(0.f, 0.f, 0.f, 0.f);
    int cnt = 0;

    const int per = seg / 4;                    // per wave: 4096
    for (int base = w * per; base < (w + 1) * per; base += 256) {
        const int j0 = base + (lane << 2);
        int4 m4 = *reinterpret_cast<const int4*>(mrow + j0);
        const unsigned bw = sbits[j0 >> 5];
        const int sh = j0 & 31;
        unsigned long long bal[4];
        bal[0] = __ballot((m4.x != 0) & ((bw >> (sh + 0)) & 1u));
        bal[1] = __ballot((m4.y != 0) & ((bw >> (sh + 1)) & 1u));
        bal[2] = __ballot((m4.z != 0) & ((bw >> (sh + 2)) & 1u));
        bal[3] = __ballot((m4.w != 0) & ((bw >> (sh + 3)) & 1u));
        #pragma unroll
        for (int s = 0; s < 4; ++s) {
            unsigned long long b = bal[s];
            while (b) {
                int t = __builtin_ctzll(b);
                b &= b - 1;
                int jj = start + base + (t << 2) + s;
                float4 hv = *reinterpret_cast<const float4*>(
                    h_sub + (size_t)jj * D + (lane << 2));
                acc.x += hv.x; acc.y += hv.y; acc.z += hv.z; acc.w += hv.w;
                cnt++;
            }
        }
    }

    __shared__ float ssum[4][D];
    __shared__ int   scnt[4];
    *reinterpret_cast<float4*>(&ssum[w][lane << 2]) = acc;
    if (lane == 0) scnt[w] = cnt;
    __syncthreads();

    float a = ssum[0][tid] + ssum[1][tid] + ssum[2][tid] + ssum[3][tid];
    psum[(size_t)blockIdx.x * D + tid] = a;
    if (tid == 0) pcnt[blockIdx.x] = scnt[0] + scnt[1] + scnt[2] + scnt[3];
}

// ---------------------------------------------------------------------------
// K2b: combine partials -> mean, cosine, classifier logits
// ---------------------------------------------------------------------------
__global__ __launch_bounds__(256) void seg_combine(
    const float* __restrict__ h_graph,  // [B][D]
    const float* __restrict__ psum,     // [B*NSPLIT][D]
    const int*   __restrict__ pcnt,     // [B*NSPLIT]
    const float* __restrict__ Wc,       // [2D][TT]
    const float* __restrict__ bc,       // [TT]
    float* __restrict__ logits,         // [B][TT]
    float* __restrict__ cos_ws)         // [B]
{
    const int i = blockIdx.x;
    const int tid = threadIdx.x;
    const int lane = tid & 63;
    const int w = tid >> 6;

    float a = 0.f;
    int c = 0;
    #pragma unroll
    for (int p = 0; p < NSPLIT; ++p) {
        a += psum[((size_t)i * NSPLIT + p) * D + tid];
        c += pcnt[i * NSPLIT + p];
    }
    a = (c > 0) ? (a / (float)c) : 0.f;
    const float g = h_graph[(size_t)i * D + tid];

    float r0 = a * a, r1 = g * g, r2 = a * g;
    #pragma unroll
    for (int m = 1; m < 64; m <<= 1) {
        r0 += __shfl_xor(r0, m);
        r1 += __shfl_xor(r1, m);
        r2 += __shfl_xor(r2, m);
    }
    __shared__ float red[4][3];
    if (lane == 0) { red[w][0] = r0; red[w][1] = r1; red[w][2] = r2; }
    __syncthreads();
    if (tid == 0) {
        float a2 = red[0][0] + red[1][0] + red[2][0] + red[3][0];
        float g2 = red[0][1] + red[1][1] + red[2][1] + red[3][1];
        float ag = red[0][2] + red[1][2] + red[2][2] + red[3][2];
        float an = sqrtf(a2), gn = sqrtf(g2);
        float cs = (c > 0) ? (ag / (fmaxf(an, 1e-12f) * fmaxf(gn, 1e-12f))) : 0.f;
        cos_ws[i] = cs;
    }

    float lg[TT];
    #pragma unroll
    for (int t = 0; t < TT; ++t)
        lg[t] = g * Wc[(size_t)tid * TT + t] + a * Wc[(size_t)(D + tid) * TT + t];
    #pragma unroll
    for (int m = 1; m < 64; m <<= 1)
        #pragma unroll
        for (int t = 0; t < TT; ++t) lg[t] += __shfl_xor(lg[t], m);
    __shared__ float lpart[4][TT];
    if (lane == 0)
        #pragma unroll
        for (int t = 0; t < TT; ++t) lpart[w][t] = lg[t];
    __syncthreads();
    if (tid < TT)
        logits[(size_t)i * TT + tid] =
            lpart[0][tid] + lpart[1][tid] + lpart[2][tid] + lpart[3][tid] + bc[tid];
}

// ---------------------------------------------------------------------------
__global__ void loss_kernel(const float* __restrict__ cos_ws,
                            float* __restrict__ out, int B)
{
    const int lane = threadIdx.x;
    float s = 0.f;
    for (int i = lane; i < B; i += 64) s += cos_ws[i];
    #pragma unroll
    for (int m = 1; m < 64; m <<= 1) s += __shfl_xor(s, m);
    if (lane == 0) out[0] = 1.0f - s / (float)B;
}

// ---------------------------------------------------------------------------
extern "C" void kernel_launch(void* const* d_in, const int* in_sizes, int n_in,
                              void* d_out, int out_size, void* d_ws, size_t ws_size,
                              hipStream_t stream)
{
    const float* h_graph = (const float*)d_in[0];
    const float* h_sub   = (const float*)d_in[1];
    const float* W1      = (const float*)d_in[2];
    const float* b1      = (const float*)d_in[3];
    const float* W2      = (const float*)d_in[4];
    const float* b2      = (const float*)d_in[5];
    const float* Wc      = (const float*)d_in[6];
    const float* bc      = (const float*)d_in[7];
    const int*   mask    = (const int*)d_in[8];

    const int B = in_sizes[0] / D;
    const int S = in_sizes[1] / D;

    float* out     = (float*)d_out;
    float* logits  = out;                       // [B*TT]
    float* loss    = out + (size_t)B * TT;      // [1]
    float* submask = loss + 1;                  // [S]

    char* ws = (char*)d_ws;
    short*    W1s    = (short*)ws;                       // 512 KB
    unsigned* gbits  = (unsigned*)(ws + 512 * 1024);     // 8 KB
    int*      pcnt   = (int*)(ws + 528 * 1024);          // 8 KB
    float*    cos_ws = (float*)(ws + 544 * 1024);        // 2 KB
    float*    psum   = (float*)(ws + 1024 * 1024);       // 2 MB

    w1_prep<<<64, 256, 0, stream>>>(W1, W1s);
    gate_mfma<<<S / 128, 512, 0, stream>>>(h_sub, W1s, b1, W2, b2, submask, gbits);
    seg_scan<<<B * NSPLIT, 256, 0, stream>>>(h_sub, mask, gbits, psum, pcnt, S);
    seg_combine<<<B, 256, 0, stream>>>(h_graph, psum, pcnt, Wc, bc, logits, cos_ws);
    loss_kernel<<<1, 64, 0, stream>>>(cos_ws, loss, B);
}

// Round 7
// 93.192 us; speedup vs baseline: 2.3328x; 1.0397x over previous
//
#include <hip/hip_runtime.h>
#include <math.h>

#define D 256
#define H 512
#define TT 10
#define THRESH 0.4f
#define KS 8          // K steps of 32 (D = 256)
#define NSPLIT 4      // scan blocks per graph

typedef __attribute__((ext_vector_type(8))) short bf16x8;
typedef __attribute__((ext_vector_type(4))) float f32x4;

__device__ inline short f2bf(float x) {
    unsigned u = __builtin_bit_cast(unsigned, x);
    u += 0x7FFFu + ((u >> 16) & 1u);
    return (short)(u >> 16);
}
__device__ inline float bf2f(short h) {
    unsigned u = ((unsigned)(unsigned short)h) << 16;
    return __builtin_bit_cast(float, u);
}

// ---------------------------------------------------------------------------
// K0: swizzle W1 [D][H] f32 -> hi/lo bf16 MFMA B-fragments in ws.
// layout (bf16x8 = 16B units): idx = ((n*2 + hl)*8 + k)*64 + lane
//   element i = W1[k*32 + (lane>>4)*8 + i][n*16 + (lane&15)]
// -> each n-tile is a contiguous 16 KB chunk (hi 8 KB | lo 8 KB).
// ---------------------------------------------------------------------------
__global__ __launch_bounds__(256) void w1_prep(const float* __restrict__ W1,
                                               short* __restrict__ W1s)
{
    const int tid = blockIdx.x * 256 + threadIdx.x;   // 16384 threads
    const int lane = tid & 63;
    const int cell = tid >> 6;                        // 0..255 = (n,k)
    const int k = cell & 7;
    const int n = cell >> 3;
    const int row0 = k * 32 + (lane >> 4) * 8;
    const int col = n * 16 + (lane & 15);
    short hi8[8], lo8[8];
    #pragma unroll
    for (int i = 0; i < 8; ++i) {
        float x = W1[(size_t)(row0 + i) * H + col];
        short h = f2bf(x);
        hi8[i] = h;
        lo8[i] = f2bf(x - bf2f(h));
    }
    size_t bh = ((((size_t)n * 2 + 0) * 8 + k) * 64 + lane) * 8;
    size_t bl = ((((size_t)n * 2 + 1) * 8 + k) * 64 + lane) * 8;
    *reinterpret_cast<bf16x8*>(W1s + bh) = *reinterpret_cast<bf16x8*>(hi8);
    *reinterpret_cast<bf16x8*>(W1s + bl) = *reinterpret_cast<bf16x8*>(lo8);
}

// ---------------------------------------------------------------------------
// K1: gate MLP, 2-term split-bf16 MFMA (A=bf16(x), B=hi+lo exact split).
// SINGLE-WAVE blocks: 64 threads, 64 rows (4 s-tiles), full H per wave.
// W1 frags stream through a private 2 x 16 KB LDS double buffer via
// global_load_lds(16B) + counted vmcnt. NO barriers anywhere.
// 1024 blocks = 4 blocks/CU (36 KB LDS), one wave per SIMD.
// ---------------------------------------------------------------------------
__global__ __launch_bounds__(64) void gate_mfma(
    const float* __restrict__ h_sub,
    const short* __restrict__ W1s,
    const float* __restrict__ b1,
    const float* __restrict__ W2,
    const float* __restrict__ b2,
    float* __restrict__ submask,
    unsigned* __restrict__ gbits)      // [S/32]
{
    __shared__ __align__(16) short sW[2][8192];   // 2 x 16 KB chunk buffers
    __shared__ float sb1[H], sw2[H];
    const int lane = threadIdx.x;      // 0..63
    const int base = blockIdx.x * 64;
    const float bb = b2[0];

    // stage b1 / W2 into LDS (prologue; drained before counted loop)
    #pragma unroll
    for (int i = 0; i < 8; ++i) {
        sb1[i * 64 + lane] = b1[i * 64 + lane];
        sw2[i * 64 + lane] = W2[i * 64 + lane];
    }

    // A fragments (hi only): 4 s-tiles x 8 k = 128 VGPR
    bf16x8 ahi[4][KS];
    #pragma unroll
    for (int s = 0; s < 4; ++s) {
        const int row = base + s * 16 + (lane & 15);
        const float* rp = h_sub + (size_t)row * D + (lane >> 4) * 8;
        #pragma unroll
        for (int k = 0; k < KS; ++k) {
            float x[8];
            *reinterpret_cast<float4*>(&x[0]) =
                *reinterpret_cast<const float4*>(rp + k * 32);
            *reinterpret_cast<float4*>(&x[4]) =
                *reinterpret_cast<const float4*>(rp + k * 32 + 4);
            short hi8[8];
            #pragma unroll
            for (int i = 0; i < 8; ++i) hi8[i] = f2bf(x[i]);
            ahi[s][k] = *reinterpret_cast<bf16x8*>(hi8);
        }
    }

    // drain ALL prologue vmem so the counted vmcnt bookkeeping is exact
    asm volatile("s_waitcnt vmcnt(0) lgkmcnt(0)" ::: "memory");

    // stage one 16 KB n-tile chunk: 16 x global_load_lds(16B)
    auto stage = [&](int c, int b) {
        const char* gp = (const char*)W1s + ((size_t)c << 14) + (size_t)lane * 16;
        char* lp0 = (char*)&sW[b][0] + lane * 16;
        #pragma unroll
        for (int i = 0; i < 16; ++i) {
            __builtin_amdgcn_global_load_lds(
                (const __attribute__((address_space(1))) void*)(gp + i * 1024),
                (__attribute__((address_space(3))) void*)(lp0 + i * 1024),
                16, 0, 0);
        }
    };

    stage(0, 0);
    stage(1, 1);

    float lp[4][4];
    #pragma unroll
    for (int s = 0; s < 4; ++s)
        #pragma unroll
        for (int j = 0; j < 4; ++j) lp[s][j] = 0.f;

    for (int c = 0; c < 32; ++c) {
        // chunk c landed; chunk c+1's 16 loads stay in flight
        if (c < 31) asm volatile("s_waitcnt vmcnt(16)" ::: "memory");
        else        asm volatile("s_waitcnt vmcnt(0)" ::: "memory");
        __builtin_amdgcn_sched_barrier(0);

        const short* buf = &sW[c & 1][0];
        f32x4 acc[4];
        #pragma unroll
        for (int s = 0; s < 4; ++s) acc[s] = (f32x4){0.f,0.f,0.f,0.f};

        #pragma unroll
        for (int k = 0; k < KS; ++k) {
            const short* fb = buf + (k * 64 + lane) * 8;
            bf16x8 bh = *reinterpret_cast<const bf16x8*>(fb);
            bf16x8 bl = *reinterpret_cast<const bf16x8*>(fb + 4096);
            #pragma unroll
            for (int s = 0; s < 4; ++s) {
                acc[s] = __builtin_amdgcn_mfma_f32_16x16x32_bf16(ahi[s][k], bl, acc[s], 0, 0, 0);
                acc[s] = __builtin_amdgcn_mfma_f32_16x16x32_bf16(ahi[s][k], bh, acc[s], 0, 0, 0);
            }
        }

        // epilogue for these 16 hidden cols: +b1, relu, dot W2
        const int h = c * 16 + (lane & 15);
        const float b1h = sb1[h], w2h = sw2[h];
        #pragma unroll
        for (int s = 0; s < 4; ++s)
            #pragma unroll
            for (int j = 0; j < 4; ++j) {
                float v = acc[s][j] + b1h;
                v = v > 0.f ? v : 0.f;
                lp[s][j] = fmaf(v, w2h, lp[s][j]);
            }

        __builtin_amdgcn_sched_barrier(0);
        if (c < 30) stage(c + 2, c & 1);   // overwrite buf we just finished
    }

    // butterfly over the 16 h-cols (low 4 lane bits)
    #pragma unroll
    for (int m = 1; m < 16; m <<= 1)
        #pragma unroll
        for (int s = 0; s < 4; ++s)
            #pragma unroll
            for (int j = 0; j < 4; ++j)
                lp[s][j] += __shfl_xor(lp[s][j], m);

    // rows: s*16 + g*4 + j  (g = lane>>4); every lane in a g-group has lp
    const int g = lane >> 4;
    unsigned b0 = 0, b1w = 0;
    float sig[4][4];
    #pragma unroll
    for (int s = 0; s < 4; ++s)
        #pragma unroll
        for (int j = 0; j < 4; ++j) {
            sig[s][j] = 1.f / (1.f + expf(-(lp[s][j] + bb)));
            const int r = s * 16 + g * 4 + j;
            if (sig[s][j] > THRESH) {
                if (r < 32) b0 |= 1u << r;
                else        b1w |= 1u << (r - 32);
            }
        }
    b0  |= __shfl_xor(b0, 16);  b0  |= __shfl_xor(b0, 32);
    b1w |= __shfl_xor(b1w, 16); b1w |= __shfl_xor(b1w, 32);
    if (lane == 0) {
        gbits[blockIdx.x * 2 + 0] = b0;
        gbits[blockIdx.x * 2 + 1] = b1w;
    }
    if ((lane & 15) == 0)
        #pragma unroll
        for (int s = 0; s < 4; ++s)
            #pragma unroll
            for (int j = 0; j < 4; ++j)
                submask[base + s * 16 + g * 4 + j] = sig[s][j];
}

// ---------------------------------------------------------------------------
// K2a: mask scan, NSPLIT blocks per graph -> partial sums/counts in ws
// ---------------------------------------------------------------------------
__global__ __launch_bounds__(256) void seg_scan(
    const float* __restrict__ h_sub,    // [S][D]
    const int*   __restrict__ mask,     // [B][S]
    const unsigned* __restrict__ gbits, // [S/32]
    float* __restrict__ psum,           // [B*NSPLIT][D]
    int*   __restrict__ pcnt,           // [B*NSPLIT]
    int S)
{
    const int i = blockIdx.x / NSPLIT;
    const int p = blockIdx.x % NSPLIT;
    const int tid = threadIdx.x;
    const int lane = tid & 63;
    const int w = tid >> 6;
    const int seg = S / NSPLIT;                 // 16384
    const int start = p * seg;
    const int* mrow = mask + (size_t)i * S + start;

    __shared__ unsigned sbits[2048 / NSPLIT];   // 512 words = 2 KB
    {
        const int nw = seg / 32;                // 512
        for (int t = tid; t < nw; t += 256) sbits[t] = gbits[(start >> 5) + t];
    }
    __syncthreads();

    float4 acc = make_float4(0.f, 0.f, 0.f, 0.f);
    int cnt = 0;

    const int per = seg / 4;                    // per wave: 4096
    for (int base = w * per; base < (w + 1) * per; base += 256) {
        const int j0 = base + (lane << 2);
        int4 m4 = *reinterpret_cast<const int4*>(mrow + j0);
        const unsigned bw = sbits[j0 >> 5];
        const int sh = j0 & 31;
        unsigned long long bal[4];
        bal[0] = __ballot((m4.x != 0) & ((bw >> (sh + 0)) & 1u));
        bal[1] = __ballot((m4.y != 0) & ((bw >> (sh + 1)) & 1u));
        bal[2] = __ballot((m4.z != 0) & ((bw >> (sh + 2)) & 1u));
        bal[3] = __ballot((m4.w != 0) & ((bw >> (sh + 3)) & 1u));
        #pragma unroll
        for (int s = 0; s < 4; ++s) {
            unsigned long long b = bal[s];
            while (b) {
                int t = __builtin_ctzll(b);
                b &= b - 1;
                int jj = start + base + (t << 2) + s;
                float4 hv = *reinterpret_cast<const float4*>(
                    h_sub + (size_t)jj * D + (lane << 2));
                acc.x += hv.x; acc.y += hv.y; acc.z += hv.z; acc.w += hv.w;
                cnt++;
            }
        }
    }

    __shared__ float ssum[4][D];
    __shared__ int   scnt[4];
    *reinterpret_cast<float4*>(&ssum[w][lane << 2]) = acc;
    if (lane == 0) scnt[w] = cnt;
    __syncthreads();

    float a = ssum[0][tid] + ssum[1][tid] + ssum[2][tid] + ssum[3][tid];
    psum[(size_t)blockIdx.x * D + tid] = a;
    if (tid == 0) pcnt[blockIdx.x] = scnt[0] + scnt[1] + scnt[2] + scnt[3];
}

// ---------------------------------------------------------------------------
// K2b: combine partials -> mean, cosine, classifier logits
// ---------------------------------------------------------------------------
__global__ __launch_bounds__(256) void seg_combine(
    const float* __restrict__ h_graph,  // [B][D]
    const float* __restrict__ psum,     // [B*NSPLIT][D]
    const int*   __restrict__ pcnt,     // [B*NSPLIT]
    const float* __restrict__ Wc,       // [2D][TT]
    const float* __restrict__ bc,       // [TT]
    float* __restrict__ logits,         // [B][TT]
    float* __restrict__ cos_ws)         // [B]
{
    const int i = blockIdx.x;
    const int tid = threadIdx.x;
    const int lane = tid & 63;
    const int w = tid >> 6;

    float a = 0.f;
    int c = 0;
    #pragma unroll
    for (int p = 0; p < NSPLIT; ++p) {
        a += psum[((size_t)i * NSPLIT + p) * D + tid];
        c += pcnt[i * NSPLIT + p];
    }
    a = (c > 0) ? (a / (float)c) : 0.f;
    const float g = h_graph[(size_t)i * D + tid];

    float r0 = a * a, r1 = g * g, r2 = a * g;
    #pragma unroll
    for (int m = 1; m < 64; m <<= 1) {
        r0 += __shfl_xor(r0, m);
        r1 += __shfl_xor(r1, m);
        r2 += __shfl_xor(r2, m);
    }
    __shared__ float red[4][3];
    if (lane == 0) { red[w][0] = r0; red[w][1] = r1; red[w][2] = r2; }
    __syncthreads();
    if (tid == 0) {
        float a2 = red[0][0] + red[1][0] + red[2][0] + red[3][0];
        float g2 = red[0][1] + red[1][1] + red[2][1] + red[3][1];
        float ag = red[0][2] + red[1][2] + red[2][2] + red[3][2];
        float an = sqrtf(a2), gn = sqrtf(g2);
        float cs = (c > 0) ? (ag / (fmaxf(an, 1e-12f) * fmaxf(gn, 1e-12f))) : 0.f;
        cos_ws[i] = cs;
    }

    float lg[TT];
    #pragma unroll
    for (int t = 0; t < TT; ++t)
        lg[t] = g * Wc[(size_t)tid * TT + t] + a * Wc[(size_t)(D + tid) * TT + t];
    #pragma unroll
    for (int m = 1; m < 64; m <<= 1)
        #pragma unroll
        for (int t = 0; t < TT; ++t) lg[t] += __shfl_xor(lg[t], m);
    __shared__ float lpart[4][TT];
    if (lane == 0)
        #pragma unroll
        for (int t = 0; t < TT; ++t) lpart[w][t] = lg[t];
    __syncthreads();
    if (tid < TT)
        logits[(size_t)i * TT + tid] =
            lpart[0][tid] + lpart[1][tid] + lpart[2][tid] + lpart[3][tid] + bc[tid];
}

// ---------------------------------------------------------------------------
__global__ void loss_kernel(const float* __restrict__ cos_ws,
                            float* __restrict__ out, int B)
{
    const int lane = threadIdx.x;
    float s = 0.f;
    for (int i = lane; i < B; i += 64) s += cos_ws[i];
    #pragma unroll
    for (int m = 1; m < 64; m <<= 1) s += __shfl_xor(s, m);
    if (lane == 0) out[0] = 1.0f - s / (float)B;
}

// ---------------------------------------------------------------------------
extern "C" void kernel_launch(void* const* d_in, const int* in_sizes, int n_in,
                              void* d_out, int out_size, void* d_ws, size_t ws_size,
                              hipStream_t stream)
{
    const float* h_graph = (const float*)d_in[0];
    const float* h_sub   = (const float*)d_in[1];
    const float* W1      = (const float*)d_in[2];
    const float* b1      = (const float*)d_in[3];
    const float* W2      = (const float*)d_in[4];
    const float* b2      = (const float*)d_in[5];
    const float* Wc      = (const float*)d_in[6];
    const float* bc      = (const float*)d_in[7];
    const int*   mask    = (const int*)d_in[8];

    const int B = in_sizes[0] / D;
    const int S = in_sizes[1] / D;

    float* out     = (float*)d_out;
    float* logits  = out;                       // [B*TT]
    float* loss    = out + (size_t)B * TT;      // [1]
    float* submask = loss + 1;                  // [S]

    char* ws = (char*)d_ws;
    short*    W1s    = (short*)ws;                       // 512 KB
    unsigned* gbits  = (unsigned*)(ws + 512 * 1024);     // 8 KB
    int*      pcnt   = (int*)(ws + 528 * 1024);          // 8 KB
    float*    cos_ws = (float*)(ws + 544 * 1024);        // 2 KB
    float*    psum   = (float*)(ws + 1024 * 1024);       // 2 MB

    w1_prep<<<64, 256, 0, stream>>>(W1, W1s);
    gate_mfma<<<S / 64, 64, 0, stream>>>(h_sub, W1s, b1, W2, b2, submask, gbits);
    seg_scan<<<B * NSPLIT, 256, 0, stream>>>(h_sub, mask, gbits, psum, pcnt, S);
    seg_combine<<<B, 256, 0, stream>>>(h_graph, psum, pcnt, Wc, bc, logits, cos_ws);
    loss_kernel<<<1, 64, 0, stream>>>(cos_ws, loss, B);
}

// Round 8
// 92.527 us; speedup vs baseline: 2.3495x; 1.0072x over previous
//
#include <hip/hip_runtime.h>
#include <math.h>

#define D 256
#define H 512
#define TT 10
#define THRESH 0.4f
#define KS 8          // K steps of 32 (D = 256)
#define NSPLIT 4      // scan blocks per graph

typedef __attribute__((ext_vector_type(8))) short bf16x8;
typedef __attribute__((ext_vector_type(4))) float f32x4;

__device__ inline short f2bf(float x) {
    unsigned u = __builtin_bit_cast(unsigned, x);
    u += 0x7FFFu + ((u >> 16) & 1u);
    return (short)(u >> 16);
}
__device__ inline float bf2f(short h) {
    unsigned u = ((unsigned)(unsigned short)h) << 16;
    return __builtin_bit_cast(float, u);
}

// ---------------------------------------------------------------------------
// K0: swizzle W1 [D][H] f32 -> single-bf16 MFMA B-fragments in ws (256 KB).
// layout (bf16x8 = 16B units): idx = (n*8 + k)*64 + lane
//   element i = W1[k*32 + (lane>>4)*8 + i][n*16 + (lane&15)]
// -> each n-tile is a contiguous 8 KB chunk.
// ---------------------------------------------------------------------------
__global__ __launch_bounds__(256) void w1_prep(const float* __restrict__ W1,
                                               short* __restrict__ W1s)
{
    const int tid = blockIdx.x * 256 + threadIdx.x;   // 16384 threads
    const int lane = tid & 63;
    const int cell = tid >> 6;                        // 0..255 = (n,k)
    const int k = cell & 7;
    const int n = cell >> 3;
    const int row0 = k * 32 + (lane >> 4) * 8;
    const int col = n * 16 + (lane & 15);
    short hi8[8];
    #pragma unroll
    for (int i = 0; i < 8; ++i)
        hi8[i] = f2bf(W1[(size_t)(row0 + i) * H + col]);
    size_t bh = (((size_t)n * 8 + k) * 64 + lane) * 8;
    *reinterpret_cast<bf16x8*>(W1s + bh) = *reinterpret_cast<bf16x8*>(hi8);
}

// ---------------------------------------------------------------------------
// K1: gate MLP, 2-term A-side split-bf16 MFMA: (ahi + alo) x bf16(W1).
// SINGLE-WAVE blocks: 64 threads, 32 rows (2 s-tiles), full H per wave.
// B streams through a private 2 x 8 KB LDS double buffer via
// global_load_lds(16B) + counted vmcnt(8). NO barriers.
// 20 KB LDS, VGPR<=256 -> 8 blocks/CU = 2 waves/SIMD (TLP latency hiding).
// ---------------------------------------------------------------------------
__global__ __launch_bounds__(64, 2) void gate_mfma(
    const float* __restrict__ h_sub,
    const short* __restrict__ W1s,
    const float* __restrict__ b1,
    const float* __restrict__ W2,
    const float* __restrict__ b2,
    float* __restrict__ submask,
    unsigned* __restrict__ gbits)      // [S/32]
{
    __shared__ __align__(16) short sW[2][4096];   // 2 x 8 KB chunk buffers
    __shared__ float sb1[H], sw2[H];
    const int lane = threadIdx.x;      // 0..63
    const int base = blockIdx.x * 32;
    const float bb = b2[0];

    // stage b1 / W2 into LDS (prologue; drained before counted loop)
    #pragma unroll
    for (int i = 0; i < 8; ++i) {
        sb1[i * 64 + lane] = b1[i * 64 + lane];
        sw2[i * 64 + lane] = W2[i * 64 + lane];
    }

    // A fragments hi+lo: 2 s-tiles x 8 k x 2 = 128 VGPR
    bf16x8 ahi[2][KS], alo[2][KS];
    #pragma unroll
    for (int s = 0; s < 2; ++s) {
        const int row = base + s * 16 + (lane & 15);
        const float* rp = h_sub + (size_t)row * D + (lane >> 4) * 8;
        #pragma unroll
        for (int k = 0; k < KS; ++k) {
            float x[8];
            *reinterpret_cast<float4*>(&x[0]) =
                *reinterpret_cast<const float4*>(rp + k * 32);
            *reinterpret_cast<float4*>(&x[4]) =
                *reinterpret_cast<const float4*>(rp + k * 32 + 4);
            short hi8[8], lo8[8];
            #pragma unroll
            for (int i = 0; i < 8; ++i) {
                short h = f2bf(x[i]);
                hi8[i] = h;
                lo8[i] = f2bf(x[i] - bf2f(h));
            }
            ahi[s][k] = *reinterpret_cast<bf16x8*>(hi8);
            alo[s][k] = *reinterpret_cast<bf16x8*>(lo8);
        }
    }

    // drain ALL prologue vmem so the counted vmcnt bookkeeping is exact
    asm volatile("s_waitcnt vmcnt(0) lgkmcnt(0)" ::: "memory");

    // stage one 8 KB n-tile chunk: 8 x global_load_lds(16B)
    auto stage = [&](int c, int b) {
        const char* gp = (const char*)W1s + ((size_t)c << 13) + (size_t)lane * 16;
        char* lp0 = (char*)&sW[b][0] + lane * 16;
        #pragma unroll
        for (int i = 0; i < 8; ++i) {
            __builtin_amdgcn_global_load_lds(
                (const __attribute__((address_space(1))) void*)(gp + i * 1024),
                (__attribute__((address_space(3))) void*)(lp0 + i * 1024),
                16, 0, 0);
        }
    };

    stage(0, 0);
    stage(1, 1);

    float lp[2][4] = {{0.f,0.f,0.f,0.f},{0.f,0.f,0.f,0.f}};

    for (int c = 0; c < 32; ++c) {
        // chunk c landed; chunk c+1's 8 loads stay in flight
        if (c < 31) asm volatile("s_waitcnt vmcnt(8)" ::: "memory");
        else        asm volatile("s_waitcnt vmcnt(0)" ::: "memory");
        __builtin_amdgcn_sched_barrier(0);

        const short* buf = &sW[c & 1][0];
        f32x4 ah[2], al[2];   // 4 independent MFMA chains
        #pragma unroll
        for (int s = 0; s < 2; ++s) {
            ah[s] = (f32x4){0.f,0.f,0.f,0.f};
            al[s] = (f32x4){0.f,0.f,0.f,0.f};
        }

        #pragma unroll
        for (int k = 0; k < KS; ++k) {
            bf16x8 bh = *reinterpret_cast<const bf16x8*>(buf + (k * 64 + lane) * 8);
            #pragma unroll
            for (int s = 0; s < 2; ++s) {
                ah[s] = __builtin_amdgcn_mfma_f32_16x16x32_bf16(ahi[s][k], bh, ah[s], 0, 0, 0);
                al[s] = __builtin_amdgcn_mfma_f32_16x16x32_bf16(alo[s][k], bh, al[s], 0, 0, 0);
            }
        }

        // epilogue for these 16 hidden cols: +b1, relu, dot W2
        const int h = c * 16 + (lane & 15);
        const float b1h = sb1[h], w2h = sw2[h];
        #pragma unroll
        for (int s = 0; s < 2; ++s)
            #pragma unroll
            for (int j = 0; j < 4; ++j) {
                float v = ah[s][j] + al[s][j] + b1h;
                v = v > 0.f ? v : 0.f;
                lp[s][j] = fmaf(v, w2h, lp[s][j]);
            }

        __builtin_amdgcn_sched_barrier(0);
        if (c < 30) stage(c + 2, c & 1);   // refill buf we just finished
    }

    // butterfly over the 16 h-cols (low 4 lane bits)
    #pragma unroll
    for (int m = 1; m < 16; m <<= 1)
        #pragma unroll
        for (int s = 0; s < 2; ++s)
            #pragma unroll
            for (int j = 0; j < 4; ++j)
                lp[s][j] += __shfl_xor(lp[s][j], m);

    // rows: s*16 + g*4 + j  (g = lane>>4)
    const int g = lane >> 4;
    unsigned bits = 0;
    float sig[2][4];
    #pragma unroll
    for (int s = 0; s < 2; ++s)
        #pragma unroll
        for (int j = 0; j < 4; ++j) {
            sig[s][j] = 1.f / (1.f + expf(-(lp[s][j] + bb)));
            if (sig[s][j] > THRESH) bits |= 1u << (s * 16 + g * 4 + j);
        }
    bits |= __shfl_xor(bits, 16);
    bits |= __shfl_xor(bits, 32);
    if (lane == 0) gbits[blockIdx.x] = bits;

    if ((lane & 15) == 0)
        #pragma unroll
        for (int s = 0; s < 2; ++s)
            #pragma unroll
            for (int j = 0; j < 4; ++j)
                submask[base + s * 16 + g * 4 + j] = sig[s][j];
}

// ---------------------------------------------------------------------------
// K2a: mask scan, NSPLIT blocks per graph -> partial sums/counts in ws
// ---------------------------------------------------------------------------
__global__ __launch_bounds__(256) void seg_scan(
    const float* __restrict__ h_sub,    // [S][D]
    const int*   __restrict__ mask,     // [B][S]
    const unsigned* __restrict__ gbits, // [S/32]
    float* __restrict__ psum,           // [B*NSPLIT][D]
    int*   __restrict__ pcnt,           // [B*NSPLIT]
    int S)
{
    const int i = blockIdx.x / NSPLIT;
    const int p = blockIdx.x % NSPLIT;
    const int tid = threadIdx.x;
    const int lane = tid & 63;
    const int w = tid >> 6;
    const int seg = S / NSPLIT;                 // 16384
    const int start = p * seg;
    const int* mrow = mask + (size_t)i * S + start;

    __shared__ unsigned sbits[2048 / NSPLIT];   // 512 words = 2 KB
    {
        const int nw = seg / 32;                // 512
        for (int t = tid; t < nw; t += 256) sbits[t] = gbits[(start >> 5) + t];
    }
    __syncthreads();

    float4 acc = make_float4(0.f, 0.f, 0.f, 0.f);
    int cnt = 0;

    const int per = seg / 4;                    // per wave: 4096
    for (int base = w * per; base < (w + 1) * per; base += 256) {
        const int j0 = base + (lane << 2);
        int4 m4 = *reinterpret_cast<const int4*>(mrow + j0);
        const unsigned bw = sbits[j0 >> 5];
        const int sh = j0 & 31;
        unsigned long long bal[4];
        bal[0] = __ballot((m4.x != 0) & ((bw >> (sh + 0)) & 1u));
        bal[1] = __ballot((m4.y != 0) & ((bw >> (sh + 1)) & 1u));
        bal[2] = __ballot((m4.z != 0) & ((bw >> (sh + 2)) & 1u));
        bal[3] = __ballot((m4.w != 0) & ((bw >> (sh + 3)) & 1u));
        #pragma unroll
        for (int s = 0; s < 4; ++s) {
            unsigned long long b = bal[s];
            while (b) {
                int t = __builtin_ctzll(b);
                b &= b - 1;
                int jj = start + base + (t << 2) + s;
                float4 hv = *reinterpret_cast<const float4*>(
                    h_sub + (size_t)jj * D + (lane << 2));
                acc.x += hv.x; acc.y += hv.y; acc.z += hv.z; acc.w += hv.w;
                cnt++;
            }
        }
    }

    __shared__ float ssum[4][D];
    __shared__ int   scnt[4];
    *reinterpret_cast<float4*>(&ssum[w][lane << 2]) = acc;
    if (lane == 0) scnt[w] = cnt;
    __syncthreads();

    float a = ssum[0][tid] + ssum[1][tid] + ssum[2][tid] + ssum[3][tid];
    psum[(size_t)blockIdx.x * D + tid] = a;
    if (tid == 0) pcnt[blockIdx.x] = scnt[0] + scnt[1] + scnt[2] + scnt[3];
}

// ---------------------------------------------------------------------------
// K2b: combine partials -> mean, cosine, classifier logits
// ---------------------------------------------------------------------------
__global__ __launch_bounds__(256) void seg_combine(
    const float* __restrict__ h_graph,  // [B][D]
    const float* __restrict__ psum,     // [B*NSPLIT][D]
    const int*   __restrict__ pcnt,     // [B*NSPLIT]
    const float* __restrict__ Wc,       // [2D][TT]
    const float* __restrict__ bc,       // [TT]
    float* __restrict__ logits,         // [B][TT]
    float* __restrict__ cos_ws)         // [B]
{
    const int i = blockIdx.x;
    const int tid = threadIdx.x;
    const int lane = tid & 63;
    const int w = tid >> 6;

    float a = 0.f;
    int c = 0;
    #pragma unroll
    for (int p = 0; p < NSPLIT; ++p) {
        a += psum[((size_t)i * NSPLIT + p) * D + tid];
        c += pcnt[i * NSPLIT + p];
    }
    a = (c > 0) ? (a / (float)c) : 0.f;
    const float g = h_graph[(size_t)i * D + tid];

    float r0 = a * a, r1 = g * g, r2 = a * g;
    #pragma unroll
    for (int m = 1; m < 64; m <<= 1) {
        r0 += __shfl_xor(r0, m);
        r1 += __shfl_xor(r1, m);
        r2 += __shfl_xor(r2, m);
    }
    __shared__ float red[4][3];
    if (lane == 0) { red[w][0] = r0; red[w][1] = r1; red[w][2] = r2; }
    __syncthreads();
    if (tid == 0) {
        float a2 = red[0][0] + red[1][0] + red[2][0] + red[3][0];
        float g2 = red[0][1] + red[1][1] + red[2][1] + red[3][1];
        float ag = red[0][2] + red[1][2] + red[2][2] + red[3][2];
        float an = sqrtf(a2), gn = sqrtf(g2);
        float cs = (c > 0) ? (ag / (fmaxf(an, 1e-12f) * fmaxf(gn, 1e-12f))) : 0.f;
        cos_ws[i] = cs;
    }

    float lg[TT];
    #pragma unroll
    for (int t = 0; t < TT; ++t)
        lg[t] = g * Wc[(size_t)tid * TT + t] + a * Wc[(size_t)(D + tid) * TT + t];
    #pragma unroll
    for (int m = 1; m < 64; m <<= 1)
        #pragma unroll
        for (int t = 0; t < TT; ++t) lg[t] += __shfl_xor(lg[t], m);
    __shared__ float lpart[4][TT];
    if (lane == 0)
        #pragma unroll
        for (int t = 0; t < TT; ++t) lpart[w][t] = lg[t];
    __syncthreads();
    if (tid < TT)
        logits[(size_t)i * TT + tid] =
            lpart[0][tid] + lpart[1][tid] + lpart[2][tid] + lpart[3][tid] + bc[tid];
}

// ---------------------------------------------------------------------------
__global__ void loss_kernel(const float* __restrict__ cos_ws,
                            float* __restrict__ out, int B)
{
    const int lane = threadIdx.x;
    float s = 0.f;
    for (int i = lane; i < B; i += 64) s += cos_ws[i];
    #pragma unroll
    for (int m = 1; m < 64; m <<= 1) s += __shfl_xor(s, m);
    if (lane == 0) out[0] = 1.0f - s / (float)B;
}

// ---------------------------------------------------------------------------
extern "C" void kernel_launch(void* const* d_in, const int* in_sizes, int n_in,
                              void* d_out, int out_size, void* d_ws, size_t ws_size,
                              hipStream_t stream)
{
    const float* h_graph = (const float*)d_in[0];
    const float* h_sub   = (const float*)d_in[1];
    const float* W1      = (const float*)d_in[2];
    const float* b1      = (const float*)d_in[3];
    const float* W2      = (const float*)d_in[4];
    const float* b2      = (const float*)d_in[5];
    const float* Wc      = (const float*)d_in[6];
    const float* bc      = (const float*)d_in[7];
    const int*   mask    = (const int*)d_in[8];

    const int B = in_sizes[0] / D;
    const int S = in_sizes[1] / D;

    float* out     = (float*)d_out;
    float* logits  = out;                       // [B*TT]
    float* loss    = out + (size_t)B * TT;      // [1]
    float* submask = loss + 1;                  // [S]

    char* ws = (char*)d_ws;
    short*    W1s    = (short*)ws;                       // 256 KB
    unsigned* gbits  = (unsigned*)(ws + 512 * 1024);     // 8 KB
    int*      pcnt   = (int*)(ws + 528 * 1024);          // 8 KB
    float*    cos_ws = (float*)(ws + 544 * 1024);        // 2 KB
    float*    psum   = (float*)(ws + 1024 * 1024);       // 2 MB

    w1_prep<<<64, 256, 0, stream>>>(W1, W1s);
    gate_mfma<<<S / 32, 64, 0, stream>>>(h_sub, W1s, b1, W2, b2, submask, gbits);
    seg_scan<<<B * NSPLIT, 256, 0, stream>>>(h_sub, mask, gbits, psum, pcnt, S);
    seg_combine<<<B, 256, 0, stream>>>(h_graph, psum, pcnt, Wc, bc, logits, cos_ws);
    loss_kernel<<<1, 64, 0, stream>>>(cos_ws, loss, B);
}

// Round 9
// 92.441 us; speedup vs baseline: 2.3517x; 1.0009x over previous
//
#include <hip/hip_runtime.h>
#include <math.h>

#define D 256
#define H 512
#define TT 10
#define THRESH 0.4f
#define KS 8          // K steps of 32 (D = 256)
#define NSPLIT 8      // scan blocks per graph

typedef __attribute__((ext_vector_type(8))) short bf16x8;
typedef __attribute__((ext_vector_type(4))) float f32x4;

__device__ inline short f2bf(float x) {
    unsigned u = __builtin_bit_cast(unsigned, x);
    u += 0x7FFFu + ((u >> 16) & 1u);
    return (short)(u >> 16);
}
__device__ inline float bf2f(short h) {
    unsigned u = ((unsigned)(unsigned short)h) << 16;
    return __builtin_bit_cast(float, u);
}

// ---------------------------------------------------------------------------
// K0: swizzle W1 [D][H] f32 -> single-bf16 MFMA B-fragments in ws (256 KB).
// layout (bf16x8 = 16B units): idx = (n*8 + k)*64 + lane
//   element i = W1[k*32 + (lane>>4)*8 + i][n*16 + (lane&15)]
// -> each n-tile is a contiguous 8 KB chunk.
// ---------------------------------------------------------------------------
__global__ __launch_bounds__(256) void w1_prep(const float* __restrict__ W1,
                                               short* __restrict__ W1s)
{
    const int tid = blockIdx.x * 256 + threadIdx.x;   // 16384 threads
    const int lane = tid & 63;
    const int cell = tid >> 6;                        // 0..255 = (n,k)
    const int k = cell & 7;
    const int n = cell >> 3;
    const int row0 = k * 32 + (lane >> 4) * 8;
    const int col = n * 16 + (lane & 15);
    short hi8[8];
    #pragma unroll
    for (int i = 0; i < 8; ++i)
        hi8[i] = f2bf(W1[(size_t)(row0 + i) * H + col]);
    size_t bh = (((size_t)n * 8 + k) * 64 + lane) * 8;
    *reinterpret_cast<bf16x8*>(W1s + bh) = *reinterpret_cast<bf16x8*>(hi8);
}

// ---------------------------------------------------------------------------
// K1: gate MLP, 2-term A-side split-bf16 MFMA: (ahi + alo) x bf16(W1).
// 256-thread blocks = 4 INDEPENDENT waves (HW caps resident workgroups/CU,
// so 1-wave blocks never reach 2 waves/SIMD — pack 4 waves per block).
// Each wave: 32 private rows, full H, private 2 x 8 KB LDS double buffer
// streamed via global_load_lds(16B) + counted vmcnt(8). One prologue
// __syncthreads (sb1/sw2 + vmcnt drain), then ZERO barriers.
// LDS 68 KB -> 2 blocks/CU = 8 waves/CU = 2 waves/SIMD.
// ---------------------------------------------------------------------------
__global__ __launch_bounds__(256, 2) void gate_mfma(
    const float* __restrict__ h_sub,
    const short* __restrict__ W1s,
    const float* __restrict__ b1,
    const float* __restrict__ W2,
    const float* __restrict__ b2,
    float* __restrict__ submask,
    unsigned* __restrict__ gbits)      // [S/32]
{
    __shared__ __align__(16) short sW[4][2][4096];   // per-wave 2 x 8 KB
    __shared__ float sb1[H], sw2[H];
    const int tid = threadIdx.x;
    const int lane = tid & 63;
    const int w = tid >> 6;            // wave id 0..3
    const int base = blockIdx.x * 128 + w * 32;
    const float bb = b2[0];

    // stage b1 / W2 into LDS (block-wide; visible after the one barrier)
    {
        int i = tid * 2;
        *reinterpret_cast<float2*>(&sb1[i]) = *reinterpret_cast<const float2*>(&b1[i]);
        *reinterpret_cast<float2*>(&sw2[i]) = *reinterpret_cast<const float2*>(&W2[i]);
    }

    // A fragments hi+lo: 2 s-tiles x 8 k x 2 = 128 VGPR
    bf16x8 ahi[2][KS], alo[2][KS];
    #pragma unroll
    for (int s = 0; s < 2; ++s) {
        const int row = base + s * 16 + (lane & 15);
        const float* rp = h_sub + (size_t)row * D + (lane >> 4) * 8;
        #pragma unroll
        for (int k = 0; k < KS; ++k) {
            float x[8];
            *reinterpret_cast<float4*>(&x[0]) =
                *reinterpret_cast<const float4*>(rp + k * 32);
            *reinterpret_cast<float4*>(&x[4]) =
                *reinterpret_cast<const float4*>(rp + k * 32 + 4);
            short hi8[8], lo8[8];
            #pragma unroll
            for (int i = 0; i < 8; ++i) {
                short h = f2bf(x[i]);
                hi8[i] = h;
                lo8[i] = f2bf(x[i] - bf2f(h));
            }
            ahi[s][k] = *reinterpret_cast<bf16x8*>(hi8);
            alo[s][k] = *reinterpret_cast<bf16x8*>(lo8);
        }
    }

    // one barrier: sb1/sw2 visible to all waves AND all prologue vmem
    // drained (hipcc emits s_waitcnt vmcnt(0) lgkmcnt(0) before s_barrier),
    // so the counted-vmcnt bookkeeping below starts from zero.
    __syncthreads();

    // stage one 8 KB n-tile chunk into THIS wave's buffer b
    auto stage = [&](int c, int b) {
        const char* gp = (const char*)W1s + ((size_t)c << 13) + (size_t)lane * 16;
        char* lp0 = (char*)&sW[w][b][0] + lane * 16;
        #pragma unroll
        for (int i = 0; i < 8; ++i) {
            __builtin_amdgcn_global_load_lds(
                (const __attribute__((address_space(1))) void*)(gp + i * 1024),
                (__attribute__((address_space(3))) void*)(lp0 + i * 1024),
                16, 0, 0);
        }
    };

    stage(0, 0);
    stage(1, 1);

    float lp[2][4] = {{0.f,0.f,0.f,0.f},{0.f,0.f,0.f,0.f}};

    for (int c = 0; c < 32; ++c) {
        // chunk c landed; chunk c+1's 8 loads stay in flight
        if (c < 31) asm volatile("s_waitcnt vmcnt(8)" ::: "memory");
        else        asm volatile("s_waitcnt vmcnt(0)" ::: "memory");
        __builtin_amdgcn_sched_barrier(0);

        const short* buf = &sW[w][c & 1][0];
        f32x4 ah[2], al[2];   // 4 independent MFMA chains
        #pragma unroll
        for (int s = 0; s < 2; ++s) {
            ah[s] = (f32x4){0.f,0.f,0.f,0.f};
            al[s] = (f32x4){0.f,0.f,0.f,0.f};
        }

        #pragma unroll
        for (int k = 0; k < KS; ++k) {
            bf16x8 bh = *reinterpret_cast<const bf16x8*>(buf + (k * 64 + lane) * 8);
            #pragma unroll
            for (int s = 0; s < 2; ++s) {
                ah[s] = __builtin_amdgcn_mfma_f32_16x16x32_bf16(ahi[s][k], bh, ah[s], 0, 0, 0);
                al[s] = __builtin_amdgcn_mfma_f32_16x16x32_bf16(alo[s][k], bh, al[s], 0, 0, 0);
            }
        }

        // epilogue for these 16 hidden cols: +b1, relu, dot W2
        const int h = c * 16 + (lane & 15);
        const float b1h = sb1[h], w2h = sw2[h];
        #pragma unroll
        for (int s = 0; s < 2; ++s)
            #pragma unroll
            for (int j = 0; j < 4; ++j) {
                float v = ah[s][j] + al[s][j] + b1h;
                v = v > 0.f ? v : 0.f;
                lp[s][j] = fmaf(v, w2h, lp[s][j]);
            }

        __builtin_amdgcn_sched_barrier(0);
        if (c < 30) stage(c + 2, c & 1);   // refill buf we just finished
    }

    // butterfly over the 16 h-cols (low 4 lane bits)
    #pragma unroll
    for (int m = 1; m < 16; m <<= 1)
        #pragma unroll
        for (int s = 0; s < 2; ++s)
            #pragma unroll
            for (int j = 0; j < 4; ++j)
                lp[s][j] += __shfl_xor(lp[s][j], m);

    // rows: s*16 + g*4 + j  (g = lane>>4)
    const int g = lane >> 4;
    unsigned bits = 0;
    float sig[2][4];
    #pragma unroll
    for (int s = 0; s < 2; ++s)
        #pragma unroll
        for (int j = 0; j < 4; ++j) {
            sig[s][j] = 1.f / (1.f + expf(-(lp[s][j] + bb)));
            if (sig[s][j] > THRESH) bits |= 1u << (s * 16 + g * 4 + j);
        }
    bits |= __shfl_xor(bits, 16);
    bits |= __shfl_xor(bits, 32);
    if (lane == 0) gbits[blockIdx.x * 4 + w] = bits;

    if ((lane & 15) == 0)
        #pragma unroll
        for (int s = 0; s < 2; ++s)
            #pragma unroll
            for (int j = 0; j < 4; ++j)
                submask[base + s * 16 + g * 4 + j] = sig[s][j];
}

// ---------------------------------------------------------------------------
// K2a: mask scan, NSPLIT blocks per graph -> partial sums/counts in ws
// ---------------------------------------------------------------------------
__global__ __launch_bounds__(256) void seg_scan(
    const float* __restrict__ h_sub,    // [S][D]
    const int*   __restrict__ mask,     // [B][S]
    const unsigned* __restrict__ gbits, // [S/32]
    float* __restrict__ psum,           // [B*NSPLIT][D]
    int*   __restrict__ pcnt,           // [B*NSPLIT]
    int S)
{
    const int i = blockIdx.x / NSPLIT;
    const int p = blockIdx.x % NSPLIT;
    const int tid = threadIdx.x;
    const int lane = tid & 63;
    const int w = tid >> 6;
    const int seg = S / NSPLIT;                 // 8192
    const int start = p * seg;
    const int* mrow = mask + (size_t)i * S + start;

    __shared__ unsigned sbits[8192 / 32];       // 256 words = 1 KB
    {
        const int nw = seg / 32;
        for (int t = tid; t < nw; t += 256) sbits[t] = gbits[(start >> 5) + t];
    }
    __syncthreads();

    float4 acc = make_float4(0.f, 0.f, 0.f, 0.f);
    int cnt = 0;

    const int per = seg / 4;                    // per wave: 2048
    for (int base = w * per; base < (w + 1) * per; base += 256) {
        const int j0 = base + (lane << 2);
        int4 m4 = *reinterpret_cast<const int4*>(mrow + j0);
        const unsigned bw = sbits[j0 >> 5];
        const int sh = j0 & 31;
        unsigned long long bal[4];
        bal[0] = __ballot((m4.x != 0) & ((bw >> (sh + 0)) & 1u));
        bal[1] = __ballot((m4.y != 0) & ((bw >> (sh + 1)) & 1u));
        bal[2] = __ballot((m4.z != 0) & ((bw >> (sh + 2)) & 1u));
        bal[3] = __ballot((m4.w != 0) & ((bw >> (sh + 3)) & 1u));
        #pragma unroll
        for (int s = 0; s < 4; ++s) {
            unsigned long long b = bal[s];
            while (b) {
                int t = __builtin_ctzll(b);
                b &= b - 1;
                int jj = start + base + (t << 2) + s;
                float4 hv = *reinterpret_cast<const float4*>(
                    h_sub + (size_t)jj * D + (lane << 2));
                acc.x += hv.x; acc.y += hv.y; acc.z += hv.z; acc.w += hv.w;
                cnt++;
            }
        }
    }

    __shared__ float ssum[4][D];
    __shared__ int   scnt[4];
    *reinterpret_cast<float4*>(&ssum[w][lane << 2]) = acc;
    if (lane == 0) scnt[w] = cnt;
    __syncthreads();

    float a = ssum[0][tid] + ssum[1][tid] + ssum[2][tid] + ssum[3][tid];
    psum[(size_t)blockIdx.x * D + tid] = a;
    if (tid == 0) pcnt[blockIdx.x] = scnt[0] + scnt[1] + scnt[2] + scnt[3];
}

// ---------------------------------------------------------------------------
// K2b: combine partials -> mean, cosine, classifier logits
// ---------------------------------------------------------------------------
__global__ __launch_bounds__(256) void seg_combine(
    const float* __restrict__ h_graph,  // [B][D]
    const float* __restrict__ psum,     // [B*NSPLIT][D]
    const int*   __restrict__ pcnt,     // [B*NSPLIT]
    const float* __restrict__ Wc,       // [2D][TT]
    const float* __restrict__ bc,       // [TT]
    float* __restrict__ logits,         // [B][TT]
    float* __restrict__ cos_ws)         // [B]
{
    const int i = blockIdx.x;
    const int tid = threadIdx.x;
    const int lane = tid & 63;
    const int w = tid >> 6;

    float a = 0.f;
    int c = 0;
    #pragma unroll
    for (int p = 0; p < NSPLIT; ++p) {
        a += psum[((size_t)i * NSPLIT + p) * D + tid];
        c += pcnt[i * NSPLIT + p];
    }
    a = (c > 0) ? (a / (float)c) : 0.f;
    const float g = h_graph[(size_t)i * D + tid];

    float r0 = a * a, r1 = g * g, r2 = a * g;
    #pragma unroll
    for (int m = 1; m < 64; m <<= 1) {
        r0 += __shfl_xor(r0, m);
        r1 += __shfl_xor(r1, m);
        r2 += __shfl_xor(r2, m);
    }
    __shared__ float red[4][3];
    if (lane == 0) { red[w][0] = r0; red[w][1] = r1; red[w][2] = r2; }
    __syncthreads();
    if (tid == 0) {
        float a2 = red[0][0] + red[1][0] + red[2][0] + red[3][0];
        float g2 = red[0][1] + red[1][1] + red[2][1] + red[3][1];
        float ag = red[0][2] + red[1][2] + red[2][2] + red[3][2];
        float an = sqrtf(a2), gn = sqrtf(g2);
        float cs = (c > 0) ? (ag / (fmaxf(an, 1e-12f) * fmaxf(gn, 1e-12f))) : 0.f;
        cos_ws[i] = cs;
    }

    float lg[TT];
    #pragma unroll
    for (int t = 0; t < TT; ++t)
        lg[t] = g * Wc[(size_t)tid * TT + t] + a * Wc[(size_t)(D + tid) * TT + t];
    #pragma unroll
    for (int m = 1; m < 64; m <<= 1)
        #pragma unroll
        for (int t = 0; t < TT; ++t) lg[t] += __shfl_xor(lg[t], m);
    __shared__ float lpart[4][TT];
    if (lane == 0)
        #pragma unroll
        for (int t = 0; t < TT; ++t) lpart[w][t] = lg[t];
    __syncthreads();
    if (tid < TT)
        logits[(size_t)i * TT + tid] =
            lpart[0][tid] + lpart[1][tid] + lpart[2][tid] + lpart[3][tid] + bc[tid];
}

// ---------------------------------------------------------------------------
__global__ void loss_kernel(const float* __restrict__ cos_ws,
                            float* __restrict__ out, int B)
{
    const int lane = threadIdx.x;
    float s = 0.f;
    for (int i = lane; i < B; i += 64) s += cos_ws[i];
    #pragma unroll
    for (int m = 1; m < 64; m <<= 1) s += __shfl_xor(s, m);
    if (lane == 0) out[0] = 1.0f - s / (float)B;
}

// ---------------------------------------------------------------------------
extern "C" void kernel_launch(void* const* d_in, const int* in_sizes, int n_in,
                              void* d_out, int out_size, void* d_ws, size_t ws_size,
                              hipStream_t stream)
{
    const float* h_graph = (const float*)d_in[0];
    const float* h_sub   = (const float*)d_in[1];
    const float* W1      = (const float*)d_in[2];
    const float* b1      = (const float*)d_in[3];
    const float* W2      = (const float*)d_in[4];
    const float* b2      = (const float*)d_in[5];
    const float* Wc      = (const float*)d_in[6];
    const float* bc      = (const float*)d_in[7];
    const int*   mask    = (const int*)d_in[8];

    const int B = in_sizes[0] / D;
    const int S = in_sizes[1] / D;

    float* out     = (float*)d_out;
    float* logits  = out;                       // [B*TT]
    float* loss    = out + (size_t)B * TT;      // [1]
    float* submask = loss + 1;                  // [S]

    char* ws = (char*)d_ws;
    short*    W1s    = (short*)ws;                       // 256 KB
    unsigned* gbits  = (unsigned*)(ws + 512 * 1024);     // 8 KB
    int*      pcnt   = (int*)(ws + 528 * 1024);          // 16 KB
    float*    cos_ws = (float*)(ws + 560 * 1024);        // 2 KB
    float*    psum   = (float*)(ws + 1024 * 1024);       // 4 MB

    w1_prep<<<64, 256, 0, stream>>>(W1, W1s);
    gate_mfma<<<S / 128, 256, 0, stream>>>(h_sub, W1s, b1, W2, b2, submask, gbits);
    seg_scan<<<B * NSPLIT, 256, 0, stream>>>(h_sub, mask, gbits, psum, pcnt, S);
    seg_combine<<<B, 256, 0, stream>>>(h_graph, psum, pcnt, Wc, bc, logits, cos_ws);
    loss_kernel<<<1, 64, 0, stream>>>(cos_ws, loss, B);
}